// Round 10
// baseline (3445.822 us; speedup 1.0000x reference)
//
#include <hip/hip_runtime.h>
#include <math.h>

#define CDIV(a,b) (((a)+(b)-1)/(b))

typedef unsigned short u16;
typedef unsigned int u32;
typedef unsigned long long u64;
typedef __attribute__((ext_vector_type(8))) short bf16x8;
typedef __attribute__((ext_vector_type(4))) float f32x4;

constexpr int Bn = 256;
constexpr int Vn = 30000;
constexpr int Hn = 512;
constexpr int Kn = 200;
constexpr int En = 300;
constexpr int E3 = 320;          // En padded for MFMA
constexpr int Kp = 224;          // K padded to 7*32
constexpr int Vc = 256;          // v-chunk per block
constexpr int VcP = Vc + 8;      // LDS row stride in u16 (bank spread)
constexpr int NCH = 120;         // 8 XCDs x 15 chunks; grid 480 <= 512 co-resident
constexpr int CPX = NCH / 8;     // 15
constexpr int Vpad = NCH * Vc;   // 30720
constexpr int KQ = 50;           // k-quads (200/4)
constexpr int NBLK = NCH * 4;    // 480
constexpr int SW1 = 64;          // W1 gemm k-slices (r7-proven)
constexpr int KSL = 480;         // W1 k-slice length
constexpr float ALPHA  = 20.0f;
constexpr float RECW   = 0.7f;
constexpr float THRC   = 0.005f;
constexpr float EPS_BN = 1e-3f;
constexpr int   NIT    = 100;

__device__ __forceinline__ float bf2f(u16 h) {
  union { unsigned u; float f; } c; c.u = (unsigned)h << 16; return c.f;
}
__device__ __forceinline__ u16 f2bf(float f) {
  union { float f; unsigned u; } c; c.f = f;
  return (u16)((c.u + 0x7fffu + ((c.u >> 16) & 1u)) >> 16);
}
__device__ __forceinline__ bf16x8 load8bf(const float* p) {
  float4 a = *(const float4*)p, b = *(const float4*)(p + 4);
  bf16x8 r;
  r[0] = (short)f2bf(a.x); r[1] = (short)f2bf(a.y);
  r[2] = (short)f2bf(a.z); r[3] = (short)f2bf(a.w);
  r[4] = (short)f2bf(b.x); r[5] = (short)f2bf(b.y);
  r[6] = (short)f2bf(b.z); r[7] = (short)f2bf(b.w);
  return r;
}

// ================= fused sinkhorn iteration + in-kernel update =================
// MODE 0: w=bm/(kernT@u) in LDS; tpart=kern@w; BARRIER; blocks<200 update ub.
// MODE 1: MODE 0 + store w to global wout (v1 for check iterations).
// MODE 2: err partials errp[c][b]=sum_v |win*(kernT@u)-bm|; BARRIER; block0 errFin.
// MODE 3: final loss: tpart=kernA@win (no barrier; sumT runs separately).
// Co-residency: grid 480 <= 2 blocks/CU x 256 CU (launch_bounds(256,2), LDS 33KB)
// -> in-kernel arrival barrier is deadlock-free. ctr is a per-launch slot,
// zeroed by memsetAsync each kernel_launch (graph-replay safe).
template<int MODE>
__global__ __launch_bounds__(256, 2)
void fusedIter(const u16* __restrict__ kernT, const u16* __restrict__ kernA,
               u16* __restrict__ ub, const u16* __restrict__ bmb,
               u16* __restrict__ wout, const u16* __restrict__ win,
               u16* __restrict__ tpart, float* __restrict__ errp,
               const float* __restrict__ abuf, int* __restrict__ frozen,
               u32* __restrict__ ctr)
{
  if (MODE != 3 && frozen[0]) return;
  const int bid = blockIdx.x;
  const int xcd = bid & 7, wid = bid >> 3;
  const int c = xcd * CPX + (wid >> 2), g = wid & 3;
  const int v0 = c * Vc, b0 = g * 64;
  const int tid = threadIdx.x;
  const int wv = tid >> 6, l = tid & 63, l15 = l & 15, lg = l >> 4;
  const int rloc = wv * 16 + l15;     // local b row (0..63) = D col
  const int bcol = b0 + rloc;         // global b
  __shared__ u16 wlds[64 * VcP];
  char* wbase = (char*)wlds;

  if (MODE == 0 || MODE == 1 || MODE == 2) {
    // ---- phase A: denom[v][b] = sum_k kernT[v][k] * u[k][b] ----
    bf16x8 uf[7];
    {
      const u16* up = ub + (size_t)bcol * Kp + lg * 8;
#pragma unroll
      for (int ks = 0; ks < 7; ++ks) uf[ks] = *(const bf16x8*)(up + ks * 32);
    }
    float e = 0.f;
    for (int vt = 0; vt < Vc / 16; ++vt) {
      const u16* ktp = kernT + (size_t)(v0 + vt * 16 + l15) * Kp + lg * 8;
      f32x4 acc = {0.f, 0.f, 0.f, 0.f};
#pragma unroll
      for (int ks = 0; ks < 7; ++ks) {
        bf16x8 kf = *(const bf16x8*)(ktp + ks * 32);
        acc = __builtin_amdgcn_mfma_f32_16x16x32_bf16(kf, uf[ks], acc, 0, 0, 0);
      }
      const int vbase = v0 + vt * 16 + lg * 4;       // global v of acc[0]
      const size_t po = (size_t)bcol * Vpad + vbase;
      u64 bq = *(const u64*)(bmb + po);
      if (MODE == 2) {
        u64 wq = *(const u64*)(win + po);
#pragma unroll
        for (int r = 0; r < 4; ++r) {
          float bm = bf2f((u16)(bq >> (16 * r)));
          float wv_ = bf2f((u16)(wq >> (16 * r)));
          e += fabsf(wv_ * acc[r] - bm);
        }
      } else {
        u64 wq = 0;
#pragma unroll
        for (int r = 0; r < 4; ++r) {
          float bm = bf2f((u16)(bq >> (16 * r)));
          float w = (vbase + r < Vn) ? bm / acc[r] : 0.f;
          wq |= (u64)f2bf(w) << (16 * r);
        }
        *(u64*)(wbase + rloc * (VcP * 2) + vt * 32 + lg * 8) = wq;
        if (MODE == 1) *(u64*)(wout + po) = wq;
      }
    }
    if (MODE == 2) {
      e += __shfl_xor(e, 16, 64);
      e += __shfl_xor(e, 32, 64);
      if (l < 16) errp[c * Bn + bcol] = e;
      // ---- barrier, then block 0 finalizes err ----
      __builtin_amdgcn_fence(__ATOMIC_RELEASE, "agent");
      __syncthreads();
      if (tid == 0) __hip_atomic_fetch_add(ctr, 1u, __ATOMIC_RELAXED, __HIP_MEMORY_SCOPE_AGENT);
      if (bid != 0) return;
      if (tid == 0) {
        while (__hip_atomic_load(ctr, __ATOMIC_RELAXED, __HIP_MEMORY_SCOPE_AGENT) < (u32)NBLK)
          __builtin_amdgcn_s_sleep(2);
      }
      __syncthreads();
      __builtin_amdgcn_fence(__ATOMIC_ACQUIRE, "agent");
      float* red = (float*)wlds;
      float s = 0.f;
      for (int cc = 0; cc < NCH; ++cc) s += errp[(size_t)cc * Bn + tid];
      red[tid] = s; __syncthreads();
      for (int st = 128; st; st >>= 1) {
        if (tid < st) red[tid] = fmaxf(red[tid], red[tid + st]);
        __syncthreads();
      }
      if (tid == 0 && red[0] <= THRC) frozen[0] = 1;
      return;
    }
    __syncthreads();
  }

  // ---- phase B: tpart[c][kq][b][r] = sum_{v in chunk} kernA[k][v] * w[b][v] ----
  f32x4 accB[13];
#pragma unroll
  for (int mt = 0; mt < 13; ++mt) accB[mt] = (f32x4){0.f, 0.f, 0.f, 0.f};
  for (int vs = 0; vs < Vc / 32; ++vs) {
    bf16x8 wf;
    if (MODE == 3) wf = *(const bf16x8*)(win + (size_t)bcol * Vpad + v0 + vs * 32 + lg * 8);
    else wf = *(const bf16x8*)(wbase + rloc * (VcP * 2) + vs * 64 + lg * 16);
    const u16* kap = kernA + (size_t)l15 * Vpad + v0 + vs * 32 + lg * 8;
#pragma unroll
    for (int mt = 0; mt < 13; ++mt) {
      bf16x8 af = *(const bf16x8*)(kap + (size_t)mt * 16 * Vpad);
      accB[mt] = __builtin_amdgcn_mfma_f32_16x16x32_bf16(af, wf, accB[mt], 0, 0, 0);
    }
  }
#pragma unroll
  for (int mt = 0; mt < 13; ++mt) {
    const int kq = mt * 4 + lg;       // k-quad index (k = kq*4 + r)
    if (kq < KQ) {
      u64 q = (u64)f2bf(accB[mt][0])
            | ((u64)f2bf(accB[mt][1]) << 16)
            | ((u64)f2bf(accB[mt][2]) << 32)
            | ((u64)f2bf(accB[mt][3]) << 48);
      *(u64*)(tpart + (((size_t)c * KQ + kq) * Bn + bcol) * 4) = q;
    }
  }
  if (MODE == 3) return;

  // ---- barrier: all tpart visible; blocks 0..199 update ub ----
  __builtin_amdgcn_fence(__ATOMIC_RELEASE, "agent");
  __syncthreads();
  if (tid == 0) __hip_atomic_fetch_add(ctr, 1u, __ATOMIC_RELAXED, __HIP_MEMORY_SCOPE_AGENT);
  if (bid >= KQ * 4) return;
  if (tid == 0) {
    while (__hip_atomic_load(ctr, __ATOMIC_RELAXED, __HIP_MEMORY_SCOPE_AGENT) < (u32)NBLK)
      __builtin_amdgcn_s_sleep(2);
  }
  __syncthreads();
  __builtin_amdgcn_fence(__ATOMIC_ACQUIRE, "agent");
  {
    const int kq = bid >> 2, bq = bid & 3;
    const int cg = tid >> 6, bloc = tid & 63;
    const int b = bq * 64 + bloc;
    f32x4 t = {0.f, 0.f, 0.f, 0.f};
    for (int cc = cg * (NCH / 4); cc < (cg + 1) * (NCH / 4); ++cc) {
      u64 qd = *(const u64*)(tpart + (((size_t)cc * KQ + kq) * Bn + b) * 4);
      t[0] += bf2f((u16)qd);         t[1] += bf2f((u16)(qd >> 16));
      t[2] += bf2f((u16)(qd >> 32)); t[3] += bf2f((u16)(qd >> 48));
    }
    f32x4* red = (f32x4*)wlds;
    red[cg * 64 + bloc] = t;
    __syncthreads();
    if (cg == 0) {
      f32x4 s = red[bloc];
#pragma unroll
      for (int gg = 1; gg < 4; ++gg) {
        f32x4 o = red[gg * 64 + bloc];
        s[0] += o[0]; s[1] += o[1]; s[2] += o[2]; s[3] += o[3];
      }
      const int k0 = kq * 4;
      u64 q = (u64)f2bf(abuf[(size_t)(k0 + 0) * Bn + b] / s[0])
            | ((u64)f2bf(abuf[(size_t)(k0 + 1) * Bn + b] / s[1]) << 16)
            | ((u64)f2bf(abuf[(size_t)(k0 + 2) * Bn + b] / s[2]) << 32)
            | ((u64)f2bf(abuf[(size_t)(k0 + 3) * Bn + b] / s[3]) << 48);
      *(u64*)(ub + (size_t)b * Kp + k0) = q;
    }
  }
}

// ================= recon logits via MFMA: r[b][v] = 1 - sum_k costT[v][k]*dt[k][b] ====
__global__ __launch_bounds__(256, 2)
void reconMF(const u16* __restrict__ costT, const u16* __restrict__ dtb,
             u16* __restrict__ rbuf)
{
  const int c = blockIdx.x, g = blockIdx.y;
  const int v0 = c * Vc, b0 = g * 64;
  const int tid = threadIdx.x;
  const int wv = tid >> 6, l = tid & 63, l15 = l & 15, lg = l >> 4;
  const int bcol = b0 + wv * 16 + l15;
  bf16x8 uf[7];
  {
    const u16* up = dtb + (size_t)bcol * Kp + lg * 8;
#pragma unroll
    for (int ks = 0; ks < 7; ++ks) uf[ks] = *(const bf16x8*)(up + ks * 32);
  }
  for (int vt = 0; vt < Vc / 16; ++vt) {
    const u16* ktp = costT + (size_t)(v0 + vt * 16 + l15) * Kp + lg * 8;
    f32x4 acc = {0.f, 0.f, 0.f, 0.f};
#pragma unroll
    for (int ks = 0; ks < 7; ++ks) {
      bf16x8 kf = *(const bf16x8*)(ktp + ks * 32);
      acc = __builtin_amdgcn_mfma_f32_16x16x32_bf16(kf, uf[ks], acc, 0, 0, 0);
    }
    const int vbase = v0 + vt * 16 + lg * 4;
    u64 q = 0;
#pragma unroll
    for (int r = 0; r < 4; ++r) q |= (u64)f2bf(1.f - acc[r]) << (16 * r);
    *(u64*)(rbuf + (size_t)bcol * Vpad + vbase) = q;
  }
}

// ================= topic-word GEMM (MFMA, hi/lo bf16 split) =================
__global__ __launch_bounds__(256)
void gemmTW(const u16* __restrict__ nth, const u16* __restrict__ ntl,
            const u16* __restrict__ nwh, const u16* __restrict__ nwl,
            u16* __restrict__ kern_bf, u16* __restrict__ kc_bf,
            u16* __restrict__ cost_bf)
{
  const int n0 = blockIdx.x * 64;
  const int tid = threadIdx.x;
  const int wv = tid >> 6, l = tid & 63, l15 = l & 15, lg = l >> 4;
  const int n = n0 + wv * 16 + l15;     // v column
  const bool nok = n < Vn;
  f32x4 acc[14];
#pragma unroll
  for (int mt = 0; mt < 14; ++mt) acc[mt] = (f32x4){0.f, 0.f, 0.f, 0.f};
  for (int kc = 0; kc < E3; kc += 32) {
    bf16x8 bh = {0,0,0,0,0,0,0,0}, bl = {0,0,0,0,0,0,0,0};
    if (nok) {
      const size_t o = (size_t)n * E3 + kc + lg * 8;
      bh = *(const bf16x8*)(nwh + o);
      bl = *(const bf16x8*)(nwl + o);
    }
#pragma unroll
    for (int mt = 0; mt < 14; ++mt) {
      const size_t ao = (size_t)(mt * 16 + l15) * E3 + kc + lg * 8;
      bf16x8 ah = *(const bf16x8*)(nth + ao);
      bf16x8 al = *(const bf16x8*)(ntl + ao);
      acc[mt] = __builtin_amdgcn_mfma_f32_16x16x32_bf16(ah, bh, acc[mt], 0, 0, 0);
      acc[mt] = __builtin_amdgcn_mfma_f32_16x16x32_bf16(ah, bl, acc[mt], 0, 0, 0);
      acc[mt] = __builtin_amdgcn_mfma_f32_16x16x32_bf16(al, bh, acc[mt], 0, 0, 0);
    }
  }
#pragma unroll
  for (int mt = 0; mt < 14; ++mt) {
#pragma unroll
    for (int r = 0; r < 4; ++r) {
      int k = mt * 16 + lg * 4 + r;
      float cf = 1.f - acc[mt][r];
      float kf = expf(-ALPHA * cf);
      size_t o = (size_t)k * Vpad + n;
      kern_bf[o] = f2bf(kf);
      kc_bf[o]   = f2bf(kf * cf);
      cost_bf[o] = f2bf(cf);
    }
  }
}

// ================= W1 encoder GEMM (r7-proven: SW1=64, KSL=480) =================
__global__ __launch_bounds__(256)
void gemmW1(const float* __restrict__ A, const float* __restrict__ B,
            float* __restrict__ part)
{
  const int bid = blockIdx.x;            // 512
  const int xcd = bid & 7, t = bid >> 3; // 0..63
  const int s = xcd * 8 + (t >> 3);      // same-s blocks share an XCD's L2
  const int nx = t & 7;
  const int n0 = nx * 64, k0 = s * KSL;
  const int tid = threadIdx.x;
  const int wv = tid >> 6, l = tid & 63, l15 = l & 15, lg = l >> 4;
  f32x4 acc[4][4];
#pragma unroll
  for (int i = 0; i < 4; ++i)
#pragma unroll
    for (int j = 0; j < 4; ++j) acc[i][j] = (f32x4){0.f, 0.f, 0.f, 0.f};

  bf16x8 aA[4], bA[4], aB[4], bB[4];

#define LDW1(KC, AF, BF)                                                        \
  { const int kk_ = (KC) + lg * 8;                                              \
    const bool ok_ = kk_ < Vn;                                                  \
    _Pragma("unroll")                                                           \
    for (int mt = 0; mt < 4; ++mt) {                                            \
      const int m_ = wv * 64 + mt * 16 + l15;                                   \
      AF[mt] = ok_ ? load8bf(A + (size_t)m_ * Vn + kk_) : (bf16x8){0,0,0,0,0,0,0,0}; \
    }                                                                           \
    _Pragma("unroll")                                                           \
    for (int nt = 0; nt < 4; ++nt) {                                            \
      const int n_ = n0 + nt * 16 + l15;                                        \
      BF[nt] = ok_ ? load8bf(B + (size_t)n_ * Vn + kk_) : (bf16x8){0,0,0,0,0,0,0,0}; \
    } }

#define FMAW1(AF, BF)                                                           \
  _Pragma("unroll")                                                             \
  for (int mt = 0; mt < 4; ++mt)                                                \
    _Pragma("unroll")                                                           \
    for (int nt = 0; nt < 4; ++nt)                                              \
      acc[mt][nt] = __builtin_amdgcn_mfma_f32_16x16x32_bf16(AF[mt], BF[nt], acc[mt][nt], 0, 0, 0);

  LDW1(k0, aA, bA);
#pragma unroll
  for (int step = 0; step < KSL / 32; ++step) {
    if ((step & 1) == 0) {
      if (step + 1 < KSL / 32) LDW1(k0 + (step + 1) * 32, aB, bB);
      FMAW1(aA, bA);
    } else {
      if (step + 1 < KSL / 32) LDW1(k0 + (step + 1) * 32, aA, bA);
      FMAW1(aB, bB);
    }
  }
#undef LDW1
#undef FMAW1

#pragma unroll
  for (int mt = 0; mt < 4; ++mt)
#pragma unroll
    for (int nt = 0; nt < 4; ++nt)
#pragma unroll
      for (int r = 0; r < 4; ++r) {
        const int m = wv * 64 + mt * 16 + lg * 4 + r;
        const int n = n0 + nt * 16 + l15;
        part[(size_t)s * (Bn * Hn) + (size_t)m * Hn + n] = acc[mt][nt][r];
      }
}

// ================= prep: transpose bf16 [Kp][Vpad] -> [Vpad][Kp] =================
__global__ void transposeK(const u16* __restrict__ src, u16* __restrict__ dst)
{
  __shared__ u16 t[32][33];
  int tx = threadIdx.x & 31, ty = threadIdx.x >> 5;  // 32 x 8
  int v0 = blockIdx.x * 32, k0 = blockIdx.y * 32;
#pragma unroll
  for (int r = 0; r < 4; ++r) t[ty + 8 * r][tx] = src[(size_t)(k0 + ty + 8 * r) * Vpad + v0 + tx];
  __syncthreads();
#pragma unroll
  for (int r = 0; r < 4; ++r) dst[(size_t)(v0 + ty + 8 * r) * Kp + k0 + tx] = t[tx][ty + 8 * r];
}

// ================= embedding converts (normalized, hi/lo split) =================
__global__ void convTemb(const float* __restrict__ temb, const float* __restrict__ rnT,
                         u16* __restrict__ nth, u16* __restrict__ ntl)
{
  int k = blockIdx.x, e = threadIdx.x;   // Kp x 320
  float v = (k < Kn && e < En) ? temb[(size_t)k * En + e] * rnT[k] : 0.f;
  u16 hi = f2bf(v);
  nth[(size_t)k * E3 + e] = hi;
  ntl[(size_t)k * E3 + e] = f2bf(v - bf2f(hi));
}

__global__ void convWemb(const float* __restrict__ wemb, const float* __restrict__ rnW,
                         u16* __restrict__ nwh, u16* __restrict__ nwl)
{
  for (size_t idx = (size_t)blockIdx.x * 256 + threadIdx.x; idx < (size_t)Vn * E3;
       idx += (size_t)gridDim.x * 256) {
    int v = (int)(idx / E3), e = (int)(idx - (size_t)v * E3);
    float x = (e < En) ? wemb[(size_t)v * En + e] * rnW[v] : 0.f;
    u16 hi = f2bf(x);
    nwh[idx] = hi;
    nwl[idx] = f2bf(x - bf2f(hi));
  }
}

// ================= generic f32 NT GEMM (W2 only) =================
__global__ __launch_bounds__(256)
void gemm_nt(const float* __restrict__ A, const float* __restrict__ Bm,
             float* __restrict__ P, int M, int N, int Kd)
{
  const int S = gridDim.z, s = blockIdx.z;
  const int k0 = (int)((long long)Kd * s / S);
  const int k1 = (int)((long long)Kd * (s + 1) / S);
  const int m0 = blockIdx.y * 64, n0 = blockIdx.x * 64;
  __shared__ float As[16][68];
  __shared__ float Bs[16][68];
  const int tid = threadIdx.x;
  const int tx = tid & 15, ty = tid >> 4;
  const int lrow = tid >> 2, lkg = (tid & 3) * 4;
  const int mi = m0 + lrow, ni = n0 + lrow;
  float acc[4][4] = {};
  for (int kc = k0; kc < k1; kc += 16) {
    float4 a4 = {0.f, 0.f, 0.f, 0.f}, b4 = {0.f, 0.f, 0.f, 0.f};
    if (mi < M) a4 = *(const float4*)&A[(size_t)mi * Kd + kc + lkg];
    if (ni < N) b4 = *(const float4*)&Bm[(size_t)ni * Kd + kc + lkg];
    As[lkg + 0][lrow] = a4.x; As[lkg + 1][lrow] = a4.y;
    As[lkg + 2][lrow] = a4.z; As[lkg + 3][lrow] = a4.w;
    Bs[lkg + 0][lrow] = b4.x; Bs[lkg + 1][lrow] = b4.y;
    Bs[lkg + 2][lrow] = b4.z; Bs[lkg + 3][lrow] = b4.w;
    __syncthreads();
#pragma unroll
    for (int kk = 0; kk < 16; ++kk) {
      float4 av = *(const float4*)&As[kk][ty * 4];
      float4 bv = *(const float4*)&Bs[kk][tx * 4];
      float a_[4] = {av.x, av.y, av.z, av.w};
      float b_[4] = {bv.x, bv.y, bv.z, bv.w};
#pragma unroll
      for (int i = 0; i < 4; ++i)
#pragma unroll
        for (int j = 0; j < 4; ++j)
          acc[i][j] += a_[i] * b_[j];
    }
    __syncthreads();
  }
  const size_t base = (size_t)s * M * N;
#pragma unroll
  for (int i = 0; i < 4; ++i) {
    int m = m0 + ty * 4 + i;
    if (m >= M) continue;
#pragma unroll
    for (int j = 0; j < 4; ++j) {
      int n = n0 + tx * 4 + j;
      if (n < N) P[base + (size_t)m * N + n] = acc[i][j];
    }
  }
}

// ================= small kernels =================
__global__ void rowNorms(const float* __restrict__ X, float* __restrict__ rn, int R, int C)
{
  int wv = threadIdx.x >> 6, lane = threadIdx.x & 63;
  int r = blockIdx.x * 4 + wv;
  if (r >= R) return;
  float s = 0.f;
  for (int c = lane; c < C; c += 64) { float x = X[(size_t)r * C + c]; s += x * x; }
#pragma unroll
  for (int m = 32; m; m >>= 1) s += __shfl_xor(s, m, 64);
  if (lane == 0) rn[r] = 1.f / fmaxf(sqrtf(s), 1e-12f);
}

__global__ void epiH(const float* __restrict__ P, const float* __restrict__ b1,
                     float* __restrict__ h, int S)
{
  int i = blockIdx.x * blockDim.x + threadIdx.x;
  if (i >= Bn * Hn) return;
  float v = b1[i & (Hn - 1)];
#pragma unroll 8
  for (int s = 0; s < S; ++s) v += P[(size_t)s * Bn * Hn + i];
  h[i] = fmaxf(v, 0.f);
}

__global__ void bnStats(const float* __restrict__ P, const float* __restrict__ b2,
                        float* __restrict__ mu, float* __restrict__ ivar, int S)
{
  int k = blockIdx.x, b = threadIdx.x;
  float z = b2[k];
  for (int s = 0; s < S; ++s) z += P[((size_t)s * Bn + b) * Kn + k];
  __shared__ float r1[256], r2[256];
  r1[b] = z; r2[b] = z * z; __syncthreads();
  for (int st = 128; st; st >>= 1) {
    if (b < st) { r1[b] += r1[b + st]; r2[b] += r2[b + st]; }
    __syncthreads();
  }
  if (b == 0) {
    float m = r1[0] / Bn, v = r2[0] / Bn - (r1[0] / Bn) * (r1[0] / Bn);
    mu[k] = m; ivar[k] = rsqrtf(v + EPS_BN);
  }
}

__global__ void bnSoftmax(const float* __restrict__ P, const float* __restrict__ b2,
                          const float* __restrict__ mu, const float* __restrict__ ivar,
                          const float* __restrict__ gamma, const float* __restrict__ beta,
                          float* __restrict__ a, u16* __restrict__ dtb, int S)
{
  int b = blockIdx.x, k = threadIdx.x;
  float zn = -1e30f;
  if (k < Kn) {
    float z = b2[k];
    for (int s = 0; s < S; ++s) z += P[((size_t)s * Bn + b) * Kn + k];
    zn = gamma[k] * (z - mu[k]) * ivar[k] + beta[k];
  }
  __shared__ float red[256];
  red[k] = zn; __syncthreads();
  for (int st = 128; st; st >>= 1) { if (k < st) red[k] = fmaxf(red[k], red[k + st]); __syncthreads(); }
  float mx = red[0]; __syncthreads();
  float e = (k < Kn) ? expf(zn - mx) : 0.f;
  red[k] = e; __syncthreads();
  for (int st = 128; st; st >>= 1) { if (k < st) red[k] += red[k + st]; __syncthreads(); }
  float dt = e / red[0];
  if (k < Kn) a[(size_t)k * Bn + b] = dt;
  if (k < Kp) dtb[(size_t)b * Kp + k] = (k < Kn) ? f2bf(dt) : (u16)0;
}

__global__ __launch_bounds__(512)
void rowSoftmax2(const float* __restrict__ bows, u16* __restrict__ bmb)
{
  int b = blockIdx.x, t = threadIdx.x;
  const float4* row = (const float4*)(bows + (size_t)b * Vn);
  __shared__ float red[512];
  float mx = -1e30f;
  for (int v4 = t; v4 < Vn / 4; v4 += 512) {
    float4 x = row[v4];
    mx = fmaxf(mx, fmaxf(fmaxf(x.x, x.y), fmaxf(x.z, x.w)));
  }
  red[t] = mx; __syncthreads();
  for (int st = 256; st; st >>= 1) { if (t < st) red[t] = fmaxf(red[t], red[t + st]); __syncthreads(); }
  mx = red[0]; __syncthreads();
  float sum = 0.f;
  for (int v4 = t; v4 < Vn / 4; v4 += 512) {
    float4 x = row[v4];
    sum += expf(x.x - mx) + expf(x.y - mx) + expf(x.z - mx) + expf(x.w - mx);
  }
  red[t] = sum; __syncthreads();
  for (int st = 256; st; st >>= 1) { if (t < st) red[t] += red[t + st]; __syncthreads(); }
  float inv = 1.f / red[0];
  for (int v4 = t; v4 < Vn / 4; v4 += 512) {
    float4 x = row[v4];
    u64 q = (u64)f2bf(expf(x.x - mx) * inv)
          | ((u64)f2bf(expf(x.y - mx) * inv) << 16)
          | ((u64)f2bf(expf(x.z - mx) * inv) << 32)
          | ((u64)f2bf(expf(x.w - mx) * inv) << 48);
    *(u64*)(bmb + (size_t)b * Vpad + v4 * 4) = q;
  }
  for (int p = t; p < (Vpad - Vn) / 4; p += 512)
    *(u64*)(bmb + (size_t)b * Vpad + Vn + p * 4) = 0;
}

__global__ void initU2(u16* __restrict__ ub)
{
  int b = blockIdx.x, k = threadIdx.x;   // Bn blocks x Kp threads
  ub[(size_t)b * Kp + k] = (k < Kn) ? f2bf(1.f / Kn) : (u16)0;
}

// t2 packed [kq][b][4] f32 (final-loss reduction, one-shot)
__global__ __launch_bounds__(256)
void sumT(const u16* __restrict__ tpart, float* __restrict__ t2)
{
  const int kq = blockIdx.x >> 2, bq = blockIdx.x & 3;
  const int cg = threadIdx.x >> 6, bloc = threadIdx.x & 63;
  const int b = bq * 64 + bloc;
  f32x4 t = {0.f, 0.f, 0.f, 0.f};
  for (int c = cg * (NCH / 4); c < (cg + 1) * (NCH / 4); ++c) {
    u64 qd = *(const u64*)(tpart + (((size_t)c * KQ + kq) * Bn + b) * 4);
    t[0] += bf2f((u16)qd);         t[1] += bf2f((u16)(qd >> 16));
    t[2] += bf2f((u16)(qd >> 32)); t[3] += bf2f((u16)(qd >> 48));
  }
  __shared__ f32x4 red[4][64];
  red[cg][bloc] = t;
  __syncthreads();
  if (cg == 0) {
    f32x4 s = red[0][bloc];
#pragma unroll
    for (int gg = 1; gg < 4; ++gg) {
      f32x4 o = red[gg][bloc];
      s[0] += o[0]; s[1] += o[1]; s[2] += o[2]; s[3] += o[3];
    }
    float4 ov; ov.x = s[0]; ov.y = s[1]; ov.z = s[2]; ov.w = s[3];
    *(float4*)&t2[(((size_t)kq * Bn) + b) * 4] = ov;
  }
}

__global__ __launch_bounds__(512)
void recPass2(const u16* __restrict__ r, const float* __restrict__ bows,
              float* __restrict__ Lb)
{
  int b = blockIdx.x, t = threadIdx.x;
  const float m = 1.0f;   // logits r = 1 - dot(dt,cost) <= 1 always
  const float4* br = (const float4*)(bows + (size_t)b * Vn);
  float se = 0.f, dot = 0.f, bs = 0.f;
  for (int v4 = t; v4 < Vn / 4; v4 += 512) {
    u64 q = *(const u64*)(r + (size_t)b * Vpad + v4 * 4);
    float4 w = br[v4];
    float x0 = bf2f((u16)q), x1 = bf2f((u16)(q >> 16));
    float x2 = bf2f((u16)(q >> 32)), x3 = bf2f((u16)(q >> 48));
    se  += expf(x0 - m) + expf(x1 - m) + expf(x2 - m) + expf(x3 - m);
    dot += w.x * x0 + w.y * x1 + w.z * x2 + w.w * x3;
    bs  += w.x + w.y + w.z + w.w;
  }
  __shared__ float red[512];
  red[t] = se; __syncthreads();
  for (int st = 256; st; st >>= 1) { if (t < st) red[t] += red[t + st]; __syncthreads(); }
  float seT = red[0]; __syncthreads();
  red[t] = dot; __syncthreads();
  for (int st = 256; st; st >>= 1) { if (t < st) red[t] += red[t + st]; __syncthreads(); }
  float dotT = red[0]; __syncthreads();
  red[t] = bs; __syncthreads();
  for (int st = 256; st; st >>= 1) { if (t < st) red[t] += red[t + st]; __syncthreads(); }
  if (t == 0) Lb[b] = dotT - (m + logf(seT)) * red[0];
}

__global__ void finalOut(const u16* __restrict__ ub, const float* __restrict__ t2,
                         const float* __restrict__ Lb, float* __restrict__ outp)
{
  int b = threadIdx.x;
  float sl = 0.f;
  for (int k = 0; k < Kn; ++k)
    sl += bf2f(ub[(size_t)b * Kp + k]) * t2[(((size_t)(k >> 2) * Bn) + b) * 4 + (k & 3)];
  __shared__ float r1[256], r2[256];
  r1[b] = sl; r2[b] = Lb[b]; __syncthreads();
  for (int st = 128; st; st >>= 1) {
    if (b < st) { r1[b] += r1[b + st]; r2[b] += r2[b + st]; }
    __syncthreads();
  }
  if (b == 0) {
    outp[0] = RECW * (-(r2[0] / (float)Bn));
    outp[1] = r1[0] / (float)Bn;
  }
}

extern "C" void kernel_launch(void* const* d_in, const int* in_sizes, int n_in,
                              void* d_out, int out_size, void* d_ws, size_t ws_size,
                              hipStream_t stream)
{
  const float* bows  = (const float*)d_in[0];
  const float* W1    = (const float*)d_in[1];
  const float* b1    = (const float*)d_in[2];
  const float* W2    = (const float*)d_in[3];
  const float* b2    = (const float*)d_in[4];
  const float* gamma = (const float*)d_in[5];
  const float* beta  = (const float*)d_in[6];
  const float* wemb  = (const float*)d_in[7];
  const float* temb  = (const float*)d_in[8];
  float* out = (float*)d_out;

  float* ws = (float*)d_ws;
  size_t off = 0;
  auto alloc = [&](size_t n) { float* p = ws + off; off += (n + 63) & ~(size_t)63; return p; };
  // R1: multi-epoch region. Epoch1: nw_hi/nw_lo (38.4MB). Epoch2: W1 partials
  // (33.5MB). Epoch3: bm_bf + vb_bf (31.5MB). Lifetimes strictly sequential.
  size_t r1_floats = (size_t)Vn * E3;
  if ((size_t)SW1 * Bn * Hn > r1_floats) r1_floats = (size_t)SW1 * Bn * Hn;
  float* R1      = alloc(r1_floats);
  u16*   kern_bf = (u16*)alloc(((size_t)Kp * Vpad + 1) / 2);
  u16*   kernT   = (u16*)alloc(((size_t)Vpad * Kp + 1) / 2);
  u16*   kc_bf   = (u16*)alloc(((size_t)Kp * Vpad + 1) / 2);
  u16*   cost_bf = (u16*)alloc(((size_t)Kp * Vpad + 1) / 2);
  u16*   costT   = (u16*)alloc(((size_t)Vpad * Kp + 1) / 2);
  u16*   nt_hi   = (u16*)alloc(((size_t)Kp * E3 + 1) / 2);
  u16*   nt_lo   = (u16*)alloc(((size_t)Kp * E3 + 1) / 2);
  u16*   ub_bf   = (u16*)alloc(((size_t)Bn * Kp + 1) / 2);
  u16*   dt_bf   = (u16*)alloc(((size_t)Bn * Kp + 1) / 2);
  u16*   tpart   = (u16*)alloc(((size_t)NCH * KQ * Bn * 4 + 1) / 2);
  float* w2buf   = alloc((size_t)4 * Bn * Kn);
  float* hbuf    = alloc((size_t)Bn * Hn);
  float* abuf    = alloc((size_t)Kn * Bn);
  float* t2      = alloc((size_t)KQ * Bn * 4);
  float* rnT     = alloc(Kn);
  float* rnW     = alloc(Vn);
  float* mu      = alloc(Kn);
  float* ivar    = alloc(Kn);
  float* errp    = alloc((size_t)NCH * Bn);
  float* Lb      = alloc(Bn);
  u32* ctrbuf = (u32*)(ws + off); off += 128;
  int* frozen = (int*)(ws + off); off += 64;
  if (off * sizeof(float) > ws_size) return;
  // R1 epoch views:
  u16*   nw_hi  = (u16*)R1;
  u16*   nw_lo  = nw_hi + (size_t)Vn * E3;
  float* w1part = R1;
  u16*   bm_bf  = (u16*)R1;
  u16*   vb_bf  = bm_bf + (size_t)Bn * Vpad;
  u16*   rbuf   = kern_bf;   // recon logits overwrite kern_bf/kernT post-loop

  hipMemsetAsync(frozen, 0, sizeof(int), stream);
  hipMemsetAsync(ctrbuf, 0, 128 * sizeof(u32), stream);

  // ---- topic_word -> kern/kc/cost bf16 (+transposes) ----
  rowNorms<<<CDIV(Kn, 4), 256, 0, stream>>>(temb, rnT, Kn, En);
  rowNorms<<<CDIV(Vn, 4), 256, 0, stream>>>(wemb, rnW, Vn, En);
  convTemb<<<Kp, E3, 0, stream>>>(temb, rnT, nt_hi, nt_lo);
  convWemb<<<4096, 256, 0, stream>>>(wemb, rnW, nw_hi, nw_lo);
  gemmTW<<<Vpad / 64, 256, 0, stream>>>(nt_hi, nt_lo, nw_hi, nw_lo, kern_bf, kc_bf, cost_bf);
  transposeK<<<dim3(Vpad / 32, Kp / 32), 256, 0, stream>>>(kern_bf, kernT);
  transposeK<<<dim3(Vpad / 32, Kp / 32), 256, 0, stream>>>(cost_bf, costT);

  // ---- encoder (W1 partials clobber nw -- dead after gemmTW) ----
  gemmW1<<<8 * SW1, 256, 0, stream>>>(bows, W1, w1part);
  epiH<<<CDIV(Bn * Hn, 256), 256, 0, stream>>>(w1part, b1, hbuf, SW1);
  {
    dim3 g(CDIV(Kn, 64), CDIV(Bn, 64), 4);
    gemm_nt<<<g, 256, 0, stream>>>(hbuf, W2, w2buf, Bn, Kn, Hn);
  }
  bnStats<<<Kn, 256, 0, stream>>>(w2buf, b2, mu, ivar, 4);
  bnSoftmax<<<Bn, 256, 0, stream>>>(w2buf, b2, mu, ivar, gamma, beta, abuf, dt_bf, 4);
  rowSoftmax2<<<Bn, 512, 0, stream>>>(bows, bm_bf);   // clobbers dead W1 partials
  initU2<<<Bn, Kp, 0, stream>>>(ub_bf);

  // ---- sinkhorn loop: ONE launch/iter (in-kernel barrier + update) ----
  int slot = 0;
  for (int it = 0; it < NIT; ++it) {
    fusedIter<0><<<NBLK, 256, 0, stream>>>(kernT, kern_bf, ub_bf, bm_bf, nullptr,
                                           nullptr, tpart, errp, abuf, frozen,
                                           ctrbuf + slot++);
    if (it % 20 == 0) {
      fusedIter<1><<<NBLK, 256, 0, stream>>>(kernT, kern_bf, ub_bf, bm_bf, vb_bf,
                                             nullptr, tpart, errp, abuf, frozen,
                                             ctrbuf + slot++);
      fusedIter<2><<<NBLK, 256, 0, stream>>>(kernT, kern_bf, ub_bf, bm_bf, nullptr,
                                             vb_bf, tpart, errp, abuf, frozen,
                                             ctrbuf + slot++);
    }
  }

  // ---- reconstruction loss (MFMA; rbuf overwrites dead kern_bf/kernT) ----
  reconMF<<<dim3(NCH, Bn / 64), 256, 0, stream>>>(costT, dt_bf, rbuf);
  recPass2<<<Bn, 512, 0, stream>>>(rbuf, bows, Lb);

  // ---- sinkhorn loss (MODE 3: no barrier; sumT + finalOut) ----
  fusedIter<3><<<NBLK, 256, 0, stream>>>(nullptr, kc_bf, ub_bf, nullptr, nullptr,
                                         vb_bf, tpart, errp, abuf, frozen,
                                         ctrbuf + slot++);
  sumT<<<KQ * 4, 256, 0, stream>>>(tpart, t2);
  finalOut<<<1, 256, 0, stream>>>(ub_bf, t2, Lb, out);
}

// Round 15
// 2291.538 us; speedup vs baseline: 1.5037x; 1.5037x over previous
//
#include <hip/hip_runtime.h>
#include <math.h>

#define CDIV(a,b) (((a)+(b)-1)/(b))

typedef unsigned short u16;
typedef unsigned long long u64;
typedef __attribute__((ext_vector_type(8))) short bf16x8;
typedef __attribute__((ext_vector_type(4))) float f32x4;

constexpr int Bn = 256;
constexpr int Vn = 30000;
constexpr int Hn = 512;
constexpr int Kn = 200;
constexpr int En = 300;
constexpr int E3 = 320;          // En padded for MFMA
constexpr int Kp = 224;          // K padded to 7*32
constexpr int Vc = 224;          // v-chunk per block
constexpr int NCH = 136;         // chunks (natural order -- XCD swizzle hurt, r7 vs r5)
constexpr int Vpad = NCH * Vc;   // 30464
constexpr int SW1 = 64;          // W1 gemm k-slices (r7-proven)
constexpr int KSL = 480;         // W1 k-slice length
constexpr float ALPHA  = 20.0f;
constexpr float RECW   = 0.7f;
constexpr float THRC   = 0.005f;
constexpr float EPS_BN = 1e-3f;
constexpr int   NIT    = 100;

__device__ __forceinline__ float bf2f(u16 h) {
  union { unsigned u; float f; } c; c.u = (unsigned)h << 16; return c.f;
}
__device__ __forceinline__ u16 f2bf(float f) {
  union { float f; unsigned u; } c; c.f = f;
  return (u16)((c.u + 0x7fffu + ((c.u >> 16) & 1u)) >> 16);
}
__device__ __forceinline__ bf16x8 load8bf(const float* p) {
  float4 a = *(const float4*)p, b = *(const float4*)(p + 4);
  bf16x8 r;
  r[0] = (short)f2bf(a.x); r[1] = (short)f2bf(a.y);
  r[2] = (short)f2bf(a.z); r[3] = (short)f2bf(a.w);
  r[4] = (short)f2bf(b.x); r[5] = (short)f2bf(b.y);
  r[6] = (short)f2bf(b.z); r[7] = (short)f2bf(b.w);
  return r;
}

// ================= fused sinkhorn iteration (MFMA bf16) =================
// MODE 0: w = bm/(kernT@u) in LDS, then tpart = kern@w partials (bf16)
// MODE 1: MODE 0 + also store w to global wout (v1 for check iterations)
// MODE 2: err partials only: errp[c][b] = sum_v |win*(kernT@u) - bm|
// MODE 3: final loss: tpart = kernA@win (win from global, phase A skipped)
// Natural dim3(NCH,4) grid: consecutive blocks stream consecutive memory
// (r5-proven; XCD-affine remap regressed the loop ~1.4us/iter in r7).
template<int MODE>
__global__ __launch_bounds__(256, 2)
void fusedAB(const u16* __restrict__ kernT, const u16* __restrict__ kernA,
             const u16* __restrict__ ub, const u16* __restrict__ bmb,
             u16* __restrict__ wout, const u16* __restrict__ win,
             u16* __restrict__ tpart, float* __restrict__ errp,
             const int* __restrict__ frozen)
{
  if (MODE != 3 && frozen[0]) return;
  const int c = blockIdx.x, g = blockIdx.y;
  const int v0 = c * Vc, b0 = g * 64;
  const int tid = threadIdx.x;
  const int wv = tid >> 6, l = tid & 63, l15 = l & 15, lg = l >> 4;
  const int rloc = wv * 16 + l15;     // local b row (0..63) = D col
  const int bcol = b0 + rloc;         // global b
  __shared__ u16 wlds[64 * Vc];
  char* wbase = (char*)wlds;
  const int sw = (rloc & 3) << 4;     // XOR bank swizzle (bits 4-5, in-range)

  if (MODE != 3) {
    // ---- phase A: denom[v][b] = sum_k kernT[v][k] * u[k][b] ----
    bf16x8 uf[7];
    {
      const u16* up = ub + (size_t)bcol * Kp + lg * 8;
#pragma unroll
      for (int ks = 0; ks < 7; ++ks) uf[ks] = *(const bf16x8*)(up + ks * 32);
    }
    float e = 0.f;
    for (int vt = 0; vt < Vc / 16; ++vt) {
      const u16* ktp = kernT + (size_t)(v0 + vt * 16 + l15) * Kp + lg * 8;
      f32x4 acc = {0.f, 0.f, 0.f, 0.f};
#pragma unroll
      for (int ks = 0; ks < 7; ++ks) {
        bf16x8 kf = *(const bf16x8*)(ktp + ks * 32);
        acc = __builtin_amdgcn_mfma_f32_16x16x32_bf16(kf, uf[ks], acc, 0, 0, 0);
      }
      const int vbase = v0 + vt * 16 + lg * 4;       // global v of acc[0]
      const size_t po = (size_t)bcol * Vpad + vbase;
      u64 bq = *(const u64*)(bmb + po);
      if (MODE == 2) {
        u64 wq = *(const u64*)(win + po);
#pragma unroll
        for (int r = 0; r < 4; ++r) {
          float bm = bf2f((u16)(bq >> (16 * r)));
          float wv_ = bf2f((u16)(wq >> (16 * r)));
          e += fabsf(wv_ * acc[r] - bm);
        }
      } else {
        u64 wq = 0;
#pragma unroll
        for (int r = 0; r < 4; ++r) {
          float bm = bf2f((u16)(bq >> (16 * r)));
          float w = (vbase + r < Vn) ? bm / acc[r] : 0.f;
          wq |= (u64)f2bf(w) << (16 * r);
        }
        *(u64*)(wbase + rloc * (Vc * 2) + ((vt * 32 + lg * 8) ^ sw)) = wq;
        if (MODE == 1) *(u64*)(wout + po) = wq;
      }
    }
    if (MODE == 2) {
      e += __shfl_xor(e, 16, 64);
      e += __shfl_xor(e, 32, 64);
      if (l < 16) errp[c * Bn + bcol] = e;
      return;
    }
    __syncthreads();
  }

  // ---- phase B: tpart[c][k][b] = sum_{v in chunk} kernA[k][v] * w[b][v] ----
  f32x4 accB[13];
#pragma unroll
  for (int mt = 0; mt < 13; ++mt) accB[mt] = (f32x4){0.f, 0.f, 0.f, 0.f};
  for (int vs = 0; vs < Vc / 32; ++vs) {
    bf16x8 wf;
    if (MODE == 3) wf = *(const bf16x8*)(win + (size_t)bcol * Vpad + v0 + vs * 32 + lg * 8);
    else wf = *(const bf16x8*)(wbase + rloc * (Vc * 2) + (((vs * 32 + lg * 8) * 2) ^ sw));
    const u16* kap = kernA + (size_t)l15 * Vpad + v0 + vs * 32 + lg * 8;
#pragma unroll
    for (int mt = 0; mt < 13; ++mt) {
      bf16x8 af = *(const bf16x8*)(kap + (size_t)mt * 16 * Vpad);
      accB[mt] = __builtin_amdgcn_mfma_f32_16x16x32_bf16(af, wf, accB[mt], 0, 0, 0);
    }
  }
#pragma unroll
  for (int mt = 0; mt < 13; ++mt) {
#pragma unroll
    for (int r = 0; r < 4; ++r) {
      int k = mt * 16 + lg * 4 + r;
      if (k < Kn) tpart[((size_t)c * Kn + k) * Bn + bcol] = f2bf(accB[mt][r]);
    }
  }
}

// ================= recon logits via MFMA: r[b][v] = 1 - sum_k costT[v][k]*dt[k][b] ====
__global__ __launch_bounds__(256, 2)
void reconMF(const u16* __restrict__ costT, const u16* __restrict__ dtb,
             u16* __restrict__ rbuf)
{
  const int c = blockIdx.x, g = blockIdx.y;
  const int v0 = c * Vc, b0 = g * 64;
  const int tid = threadIdx.x;
  const int wv = tid >> 6, l = tid & 63, l15 = l & 15, lg = l >> 4;
  const int bcol = b0 + wv * 16 + l15;
  bf16x8 uf[7];
  {
    const u16* up = dtb + (size_t)bcol * Kp + lg * 8;
#pragma unroll
    for (int ks = 0; ks < 7; ++ks) uf[ks] = *(const bf16x8*)(up + ks * 32);
  }
  for (int vt = 0; vt < Vc / 16; ++vt) {
    const u16* ktp = costT + (size_t)(v0 + vt * 16 + l15) * Kp + lg * 8;
    f32x4 acc = {0.f, 0.f, 0.f, 0.f};
#pragma unroll
    for (int ks = 0; ks < 7; ++ks) {
      bf16x8 kf = *(const bf16x8*)(ktp + ks * 32);
      acc = __builtin_amdgcn_mfma_f32_16x16x32_bf16(kf, uf[ks], acc, 0, 0, 0);
    }
    const int vbase = v0 + vt * 16 + lg * 4;
    u64 q = 0;
#pragma unroll
    for (int r = 0; r < 4; ++r) q |= (u64)f2bf(1.f - acc[r]) << (16 * r);
    *(u64*)(rbuf + (size_t)bcol * Vpad + vbase) = q;
  }
}

// ================= topic-word GEMM (MFMA, hi/lo bf16 split) =================
__global__ __launch_bounds__(256)
void gemmTW(const u16* __restrict__ nth, const u16* __restrict__ ntl,
            const u16* __restrict__ nwh, const u16* __restrict__ nwl,
            u16* __restrict__ kern_bf, u16* __restrict__ kc_bf,
            u16* __restrict__ cost_bf)
{
  const int n0 = blockIdx.x * 64;
  const int tid = threadIdx.x;
  const int wv = tid >> 6, l = tid & 63, l15 = l & 15, lg = l >> 4;
  const int n = n0 + wv * 16 + l15;     // v column
  const bool nok = n < Vn;
  f32x4 acc[14];
#pragma unroll
  for (int mt = 0; mt < 14; ++mt) acc[mt] = (f32x4){0.f, 0.f, 0.f, 0.f};
  for (int kc = 0; kc < E3; kc += 32) {
    bf16x8 bh = {0,0,0,0,0,0,0,0}, bl = {0,0,0,0,0,0,0,0};
    if (nok) {
      const size_t o = (size_t)n * E3 + kc + lg * 8;
      bh = *(const bf16x8*)(nwh + o);
      bl = *(const bf16x8*)(nwl + o);
    }
#pragma unroll
    for (int mt = 0; mt < 14; ++mt) {
      const size_t ao = (size_t)(mt * 16 + l15) * E3 + kc + lg * 8;
      bf16x8 ah = *(const bf16x8*)(nth + ao);
      bf16x8 al = *(const bf16x8*)(ntl + ao);
      acc[mt] = __builtin_amdgcn_mfma_f32_16x16x32_bf16(ah, bh, acc[mt], 0, 0, 0);
      acc[mt] = __builtin_amdgcn_mfma_f32_16x16x32_bf16(ah, bl, acc[mt], 0, 0, 0);
      acc[mt] = __builtin_amdgcn_mfma_f32_16x16x32_bf16(al, bh, acc[mt], 0, 0, 0);
    }
  }
#pragma unroll
  for (int mt = 0; mt < 14; ++mt) {
#pragma unroll
    for (int r = 0; r < 4; ++r) {
      int k = mt * 16 + lg * 4 + r;
      float cf = 1.f - acc[mt][r];
      float kf = expf(-ALPHA * cf);
      size_t o = (size_t)k * Vpad + n;
      kern_bf[o] = f2bf(kf);
      kc_bf[o]   = f2bf(kf * cf);
      cost_bf[o] = f2bf(cf);
    }
  }
}

// ================= W1 encoder GEMM (r7-proven: SW1=64, KSL=480, dbuf) =========
__global__ __launch_bounds__(256)
void gemmW1(const float* __restrict__ A, const float* __restrict__ B,
            float* __restrict__ part)
{
  const int bid = blockIdx.x;            // 512
  const int xcd = bid & 7, t = bid >> 3; // 0..63
  const int s = xcd * 8 + (t >> 3);      // same-s blocks share an XCD's L2
  const int nx = t & 7;
  const int n0 = nx * 64, k0 = s * KSL;
  const int tid = threadIdx.x;
  const int wv = tid >> 6, l = tid & 63, l15 = l & 15, lg = l >> 4;
  f32x4 acc[4][4];
#pragma unroll
  for (int i = 0; i < 4; ++i)
#pragma unroll
    for (int j = 0; j < 4; ++j) acc[i][j] = (f32x4){0.f, 0.f, 0.f, 0.f};

  bf16x8 aA[4], bA[4], aB[4], bB[4];

#define LDW1(KC, AF, BF)                                                        \
  { const int kk_ = (KC) + lg * 8;                                              \
    const bool ok_ = kk_ < Vn;                                                  \
    _Pragma("unroll")                                                           \
    for (int mt = 0; mt < 4; ++mt) {                                            \
      const int m_ = wv * 64 + mt * 16 + l15;                                   \
      AF[mt] = ok_ ? load8bf(A + (size_t)m_ * Vn + kk_) : (bf16x8){0,0,0,0,0,0,0,0}; \
    }                                                                           \
    _Pragma("unroll")                                                           \
    for (int nt = 0; nt < 4; ++nt) {                                            \
      const int n_ = n0 + nt * 16 + l15;                                        \
      BF[nt] = ok_ ? load8bf(B + (size_t)n_ * Vn + kk_) : (bf16x8){0,0,0,0,0,0,0,0}; \
    } }

#define FMAW1(AF, BF)                                                           \
  _Pragma("unroll")                                                             \
  for (int mt = 0; mt < 4; ++mt)                                                \
    _Pragma("unroll")                                                           \
    for (int nt = 0; nt < 4; ++nt)                                              \
      acc[mt][nt] = __builtin_amdgcn_mfma_f32_16x16x32_bf16(AF[mt], BF[nt], acc[mt][nt], 0, 0, 0);

  LDW1(k0, aA, bA);
#pragma unroll
  for (int step = 0; step < KSL / 32; ++step) {
    if ((step & 1) == 0) {
      if (step + 1 < KSL / 32) LDW1(k0 + (step + 1) * 32, aB, bB);
      FMAW1(aA, bA);
    } else {
      if (step + 1 < KSL / 32) LDW1(k0 + (step + 1) * 32, aA, bA);
      FMAW1(aB, bB);
    }
  }
#undef LDW1
#undef FMAW1

#pragma unroll
  for (int mt = 0; mt < 4; ++mt)
#pragma unroll
    for (int nt = 0; nt < 4; ++nt)
#pragma unroll
      for (int r = 0; r < 4; ++r) {
        const int m = wv * 64 + mt * 16 + lg * 4 + r;
        const int n = n0 + nt * 16 + l15;
        part[(size_t)s * (Bn * Hn) + (size_t)m * Hn + n] = acc[mt][nt][r];
      }
}

// ================= prep: transpose bf16 [Kp][Vpad] -> [Vpad][Kp] =================
__global__ void transposeK(const u16* __restrict__ src, u16* __restrict__ dst)
{
  __shared__ u16 t[32][33];
  int tx = threadIdx.x & 31, ty = threadIdx.x >> 5;  // 32 x 8
  int v0 = blockIdx.x * 32, k0 = blockIdx.y * 32;
#pragma unroll
  for (int r = 0; r < 4; ++r) t[ty + 8 * r][tx] = src[(size_t)(k0 + ty + 8 * r) * Vpad + v0 + tx];
  __syncthreads();
#pragma unroll
  for (int r = 0; r < 4; ++r) dst[(size_t)(v0 + ty + 8 * r) * Kp + k0 + tx] = t[tx][ty + 8 * r];
}

// ================= embedding converts (normalized, hi/lo split) =================
__global__ void convTemb(const float* __restrict__ temb, const float* __restrict__ rnT,
                         u16* __restrict__ nth, u16* __restrict__ ntl)
{
  int k = blockIdx.x, e = threadIdx.x;   // Kp x 320
  float v = (k < Kn && e < En) ? temb[(size_t)k * En + e] * rnT[k] : 0.f;
  u16 hi = f2bf(v);
  nth[(size_t)k * E3 + e] = hi;
  ntl[(size_t)k * E3 + e] = f2bf(v - bf2f(hi));
}

__global__ void convWemb(const float* __restrict__ wemb, const float* __restrict__ rnW,
                         u16* __restrict__ nwh, u16* __restrict__ nwl)
{
  for (size_t idx = (size_t)blockIdx.x * 256 + threadIdx.x; idx < (size_t)Vn * E3;
       idx += (size_t)gridDim.x * 256) {
    int v = (int)(idx / E3), e = (int)(idx - (size_t)v * E3);
    float x = (e < En) ? wemb[(size_t)v * En + e] * rnW[v] : 0.f;
    u16 hi = f2bf(x);
    nwh[idx] = hi;
    nwl[idx] = f2bf(x - bf2f(hi));
  }
}

// ================= generic f32 NT GEMM (W2 only) =================
__global__ __launch_bounds__(256)
void gemm_nt(const float* __restrict__ A, const float* __restrict__ Bm,
             float* __restrict__ P, int M, int N, int Kd)
{
  const int S = gridDim.z, s = blockIdx.z;
  const int k0 = (int)((long long)Kd * s / S);
  const int k1 = (int)((long long)Kd * (s + 1) / S);
  const int m0 = blockIdx.y * 64, n0 = blockIdx.x * 64;
  __shared__ float As[16][68];
  __shared__ float Bs[16][68];
  const int tid = threadIdx.x;
  const int tx = tid & 15, ty = tid >> 4;
  const int lrow = tid >> 2, lkg = (tid & 3) * 4;
  const int mi = m0 + lrow, ni = n0 + lrow;
  float acc[4][4] = {};
  for (int kc = k0; kc < k1; kc += 16) {
    float4 a4 = {0.f, 0.f, 0.f, 0.f}, b4 = {0.f, 0.f, 0.f, 0.f};
    if (mi < M) a4 = *(const float4*)&A[(size_t)mi * Kd + kc + lkg];
    if (ni < N) b4 = *(const float4*)&Bm[(size_t)ni * Kd + kc + lkg];
    As[lkg + 0][lrow] = a4.x; As[lkg + 1][lrow] = a4.y;
    As[lkg + 2][lrow] = a4.z; As[lkg + 3][lrow] = a4.w;
    Bs[lkg + 0][lrow] = b4.x; Bs[lkg + 1][lrow] = b4.y;
    Bs[lkg + 2][lrow] = b4.z; Bs[lkg + 3][lrow] = b4.w;
    __syncthreads();
#pragma unroll
    for (int kk = 0; kk < 16; ++kk) {
      float4 av = *(const float4*)&As[kk][ty * 4];
      float4 bv = *(const float4*)&Bs[kk][tx * 4];
      float a_[4] = {av.x, av.y, av.z, av.w};
      float b_[4] = {bv.x, bv.y, bv.z, bv.w};
#pragma unroll
      for (int i = 0; i < 4; ++i)
#pragma unroll
        for (int j = 0; j < 4; ++j)
          acc[i][j] += a_[i] * b_[j];
    }
    __syncthreads();
  }
  const size_t base = (size_t)s * M * N;
#pragma unroll
  for (int i = 0; i < 4; ++i) {
    int m = m0 + ty * 4 + i;
    if (m >= M) continue;
#pragma unroll
    for (int j = 0; j < 4; ++j) {
      int n = n0 + tx * 4 + j;
      if (n < N) P[base + (size_t)m * N + n] = acc[i][j];
    }
  }
}

// ================= small kernels =================
__global__ void rowNorms(const float* __restrict__ X, float* __restrict__ rn, int R, int C)
{
  int wv = threadIdx.x >> 6, lane = threadIdx.x & 63;
  int r = blockIdx.x * 4 + wv;
  if (r >= R) return;
  float s = 0.f;
  for (int c = lane; c < C; c += 64) { float x = X[(size_t)r * C + c]; s += x * x; }
#pragma unroll
  for (int m = 32; m; m >>= 1) s += __shfl_xor(s, m, 64);
  if (lane == 0) rn[r] = 1.f / fmaxf(sqrtf(s), 1e-12f);
}

__global__ void epiH(const float* __restrict__ P, const float* __restrict__ b1,
                     float* __restrict__ h, int S)
{
  int i = blockIdx.x * blockDim.x + threadIdx.x;
  if (i >= Bn * Hn) return;
  float v = b1[i & (Hn - 1)];
#pragma unroll 8
  for (int s = 0; s < S; ++s) v += P[(size_t)s * Bn * Hn + i];
  h[i] = fmaxf(v, 0.f);
}

__global__ void bnStats(const float* __restrict__ P, const float* __restrict__ b2,
                        float* __restrict__ mu, float* __restrict__ ivar, int S)
{
  int k = blockIdx.x, b = threadIdx.x;
  float z = b2[k];
  for (int s = 0; s < S; ++s) z += P[((size_t)s * Bn + b) * Kn + k];
  __shared__ float r1[256], r2[256];
  r1[b] = z; r2[b] = z * z; __syncthreads();
  for (int st = 128; st; st >>= 1) {
    if (b < st) { r1[b] += r1[b + st]; r2[b] += r2[b + st]; }
    __syncthreads();
  }
  if (b == 0) {
    float m = r1[0] / Bn, v = r2[0] / Bn - (r1[0] / Bn) * (r1[0] / Bn);
    mu[k] = m; ivar[k] = rsqrtf(v + EPS_BN);
  }
}

__global__ void bnSoftmax(const float* __restrict__ P, const float* __restrict__ b2,
                          const float* __restrict__ mu, const float* __restrict__ ivar,
                          const float* __restrict__ gamma, const float* __restrict__ beta,
                          float* __restrict__ a, u16* __restrict__ dtb, int S)
{
  int b = blockIdx.x, k = threadIdx.x;
  float zn = -1e30f;
  if (k < Kn) {
    float z = b2[k];
    for (int s = 0; s < S; ++s) z += P[((size_t)s * Bn + b) * Kn + k];
    zn = gamma[k] * (z - mu[k]) * ivar[k] + beta[k];
  }
  __shared__ float red[256];
  red[k] = zn; __syncthreads();
  for (int st = 128; st; st >>= 1) { if (k < st) red[k] = fmaxf(red[k], red[k + st]); __syncthreads(); }
  float mx = red[0]; __syncthreads();
  float e = (k < Kn) ? expf(zn - mx) : 0.f;
  red[k] = e; __syncthreads();
  for (int st = 128; st; st >>= 1) { if (k < st) red[k] += red[k + st]; __syncthreads(); }
  float dt = e / red[0];
  if (k < Kn) a[(size_t)k * Bn + b] = dt;
  if (k < Kp) dtb[(size_t)b * Kp + k] = (k < Kn) ? f2bf(dt) : (u16)0;
}

__global__ __launch_bounds__(512)
void rowSoftmax2(const float* __restrict__ bows, u16* __restrict__ bmb)
{
  int b = blockIdx.x, t = threadIdx.x;
  const float4* row = (const float4*)(bows + (size_t)b * Vn);
  __shared__ float red[512];
  float mx = -1e30f;
  for (int v4 = t; v4 < Vn / 4; v4 += 512) {
    float4 x = row[v4];
    mx = fmaxf(mx, fmaxf(fmaxf(x.x, x.y), fmaxf(x.z, x.w)));
  }
  red[t] = mx; __syncthreads();
  for (int st = 256; st; st >>= 1) { if (t < st) red[t] = fmaxf(red[t], red[t + st]); __syncthreads(); }
  mx = red[0]; __syncthreads();
  float sum = 0.f;
  for (int v4 = t; v4 < Vn / 4; v4 += 512) {
    float4 x = row[v4];
    sum += expf(x.x - mx) + expf(x.y - mx) + expf(x.z - mx) + expf(x.w - mx);
  }
  red[t] = sum; __syncthreads();
  for (int st = 256; st; st >>= 1) { if (t < st) red[t] += red[t + st]; __syncthreads(); }
  float inv = 1.f / red[0];
  for (int v4 = t; v4 < Vn / 4; v4 += 512) {
    float4 x = row[v4];
    u64 q = (u64)f2bf(expf(x.x - mx) * inv)
          | ((u64)f2bf(expf(x.y - mx) * inv) << 16)
          | ((u64)f2bf(expf(x.z - mx) * inv) << 32)
          | ((u64)f2bf(expf(x.w - mx) * inv) << 48);
    *(u64*)(bmb + (size_t)b * Vpad + v4 * 4) = q;
  }
  for (int p = t; p < (Vpad - Vn) / 4; p += 512)
    *(u64*)(bmb + (size_t)b * Vpad + Vn + p * 4) = 0;
}

__global__ void initU2(u16* __restrict__ ub)
{
  int b = blockIdx.x, k = threadIdx.x;   // Bn blocks x Kp threads
  ub[(size_t)b * Kp + k] = (k < Kn) ? f2bf(1.f / Kn) : (u16)0;
}

// 200 blocks (one k each); 64 b-quads x 4 c-groups; LDS reduce over c-groups.
__global__ __launch_bounds__(256)
void updateU2(const u16* __restrict__ tpart, const float* __restrict__ a,
              u16* __restrict__ ub, const int* __restrict__ frozen)
{
  if (frozen[0]) return;
  const int k = blockIdx.x;
  const int cg = threadIdx.x >> 6, q = threadIdx.x & 63;
  const int b0 = q * 4;
  f32x4 t = {0.f, 0.f, 0.f, 0.f};
  for (int c = cg * (NCH / 4); c < (cg + 1) * (NCH / 4); ++c) {
    u64 qd = *(const u64*)(tpart + ((size_t)c * Kn + k) * Bn + b0);
    t[0] += bf2f((u16)qd);         t[1] += bf2f((u16)(qd >> 16));
    t[2] += bf2f((u16)(qd >> 32)); t[3] += bf2f((u16)(qd >> 48));
  }
  __shared__ f32x4 red[4][64];
  red[cg][q] = t;
  __syncthreads();
  if (cg == 0) {
    f32x4 s = red[0][q];
#pragma unroll
    for (int gg = 1; gg < 4; ++gg) {
      f32x4 o = red[gg][q];
      s[0] += o[0]; s[1] += o[1]; s[2] += o[2]; s[3] += o[3];
    }
    float4 av = *(const float4*)&a[(size_t)k * Bn + b0];
    ub[(size_t)(b0 + 0) * Kp + k] = f2bf(av.x / s[0]);
    ub[(size_t)(b0 + 1) * Kp + k] = f2bf(av.y / s[1]);
    ub[(size_t)(b0 + 2) * Kp + k] = f2bf(av.z / s[2]);
    ub[(size_t)(b0 + 3) * Kp + k] = f2bf(av.w / s[3]);
  }
}

__global__ __launch_bounds__(256)
void sumT(const u16* __restrict__ tpart, float* __restrict__ t2)
{
  const int k = blockIdx.x;
  const int cg = threadIdx.x >> 6, q = threadIdx.x & 63;
  const int b0 = q * 4;
  f32x4 t = {0.f, 0.f, 0.f, 0.f};
  for (int c = cg * (NCH / 4); c < (cg + 1) * (NCH / 4); ++c) {
    u64 qd = *(const u64*)(tpart + ((size_t)c * Kn + k) * Bn + b0);
    t[0] += bf2f((u16)qd);         t[1] += bf2f((u16)(qd >> 16));
    t[2] += bf2f((u16)(qd >> 32)); t[3] += bf2f((u16)(qd >> 48));
  }
  __shared__ f32x4 red[4][64];
  red[cg][q] = t;
  __syncthreads();
  if (cg == 0) {
    f32x4 s = red[0][q];
#pragma unroll
    for (int gg = 1; gg < 4; ++gg) {
      f32x4 o = red[gg][q];
      s[0] += o[0]; s[1] += o[1]; s[2] += o[2]; s[3] += o[3];
    }
    float4 ov; ov.x = s[0]; ov.y = s[1]; ov.z = s[2]; ov.w = s[3];
    *(float4*)&t2[(size_t)k * Bn + b0] = ov;
  }
}

__global__ void errFin(const float* __restrict__ errp, int nc, int* __restrict__ frozen)
{
  if (frozen[0]) return;
  int b = threadIdx.x;
  float s = 0.f;
  for (int c = 0; c < nc; ++c) s += errp[(size_t)c * Bn + b];
  __shared__ float red[256];
  red[b] = s; __syncthreads();
  for (int st = 128; st; st >>= 1) { if (b < st) red[b] = fmaxf(red[b], red[b + st]); __syncthreads(); }
  if (b == 0 && red[0] <= THRC) frozen[0] = 1;
}

__global__ __launch_bounds__(512)
void recPass2(const u16* __restrict__ r, const float* __restrict__ bows,
              float* __restrict__ Lb)
{
  int b = blockIdx.x, t = threadIdx.x;
  const float m = 1.0f;   // logits r = 1 - dot(dt,cost) <= 1 always
  const float4* br = (const float4*)(bows + (size_t)b * Vn);
  float se = 0.f, dot = 0.f, bs = 0.f;
  for (int v4 = t; v4 < Vn / 4; v4 += 512) {
    u64 q = *(const u64*)(r + (size_t)b * Vpad + v4 * 4);
    float4 w = br[v4];
    float x0 = bf2f((u16)q), x1 = bf2f((u16)(q >> 16));
    float x2 = bf2f((u16)(q >> 32)), x3 = bf2f((u16)(q >> 48));
    se  += expf(x0 - m) + expf(x1 - m) + expf(x2 - m) + expf(x3 - m);
    dot += w.x * x0 + w.y * x1 + w.z * x2 + w.w * x3;
    bs  += w.x + w.y + w.z + w.w;
  }
  __shared__ float red[512];
  red[t] = se; __syncthreads();
  for (int st = 256; st; st >>= 1) { if (t < st) red[t] += red[t + st]; __syncthreads(); }
  float seT = red[0]; __syncthreads();
  red[t] = dot; __syncthreads();
  for (int st = 256; st; st >>= 1) { if (t < st) red[t] += red[t + st]; __syncthreads(); }
  float dotT = red[0]; __syncthreads();
  red[t] = bs; __syncthreads();
  for (int st = 256; st; st >>= 1) { if (t < st) red[t] += red[t + st]; __syncthreads(); }
  if (t == 0) Lb[b] = dotT - (m + logf(seT)) * red[0];
}

__global__ void finalOut(const u16* __restrict__ ub, const float* __restrict__ t2,
                         const float* __restrict__ Lb, float* __restrict__ outp)
{
  int b = threadIdx.x;
  float sl = 0.f;
  for (int k = 0; k < Kn; ++k) sl += bf2f(ub[(size_t)b * Kp + k]) * t2[(size_t)k * Bn + b];
  __shared__ float r1[256], r2[256];
  r1[b] = sl; r2[b] = Lb[b]; __syncthreads();
  for (int st = 128; st; st >>= 1) {
    if (b < st) { r1[b] += r1[b + st]; r2[b] += r2[b + st]; }
    __syncthreads();
  }
  if (b == 0) {
    outp[0] = RECW * (-(r2[0] / (float)Bn));
    outp[1] = r1[0] / (float)Bn;
  }
}

extern "C" void kernel_launch(void* const* d_in, const int* in_sizes, int n_in,
                              void* d_out, int out_size, void* d_ws, size_t ws_size,
                              hipStream_t stream)
{
  const float* bows  = (const float*)d_in[0];
  const float* W1    = (const float*)d_in[1];
  const float* b1    = (const float*)d_in[2];
  const float* W2    = (const float*)d_in[3];
  const float* b2    = (const float*)d_in[4];
  const float* gamma = (const float*)d_in[5];
  const float* beta  = (const float*)d_in[6];
  const float* wemb  = (const float*)d_in[7];
  const float* temb  = (const float*)d_in[8];
  float* out = (float*)d_out;

  float* ws = (float*)d_ws;
  size_t off = 0;
  auto alloc = [&](size_t n) { float* p = ws + off; off += (n + 63) & ~(size_t)63; return p; };
  // R1: multi-epoch region. Epoch1: nw_hi/nw_lo (38.4MB). Epoch2: W1 partials
  // (33.5MB). Epoch3: bm_bf + vb_bf (31.2MB). Lifetimes strictly sequential.
  size_t r1_floats = (size_t)Vn * E3;
  if ((size_t)SW1 * Bn * Hn > r1_floats) r1_floats = (size_t)SW1 * Bn * Hn;
  float* R1      = alloc(r1_floats);
  u16*   kern_bf = (u16*)alloc(((size_t)Kp * Vpad + 1) / 2);
  u16*   kernT   = (u16*)alloc(((size_t)Vpad * Kp + 1) / 2);
  u16*   kc_bf   = (u16*)alloc(((size_t)Kp * Vpad + 1) / 2);
  u16*   cost_bf = (u16*)alloc(((size_t)Kp * Vpad + 1) / 2);
  u16*   costT   = (u16*)alloc(((size_t)Vpad * Kp + 1) / 2);
  u16*   nt_hi   = (u16*)alloc(((size_t)Kp * E3 + 1) / 2);
  u16*   nt_lo   = (u16*)alloc(((size_t)Kp * E3 + 1) / 2);
  u16*   ub_bf   = (u16*)alloc(((size_t)Bn * Kp + 1) / 2);
  u16*   dt_bf   = (u16*)alloc(((size_t)Bn * Kp + 1) / 2);
  u16*   tpart   = (u16*)alloc(((size_t)NCH * Kn * Bn + 1) / 2);
  float* w2buf   = alloc((size_t)4 * Bn * Kn);
  float* hbuf    = alloc((size_t)Bn * Hn);
  float* abuf    = alloc((size_t)Kn * Bn);
  float* t2      = alloc((size_t)Kn * Bn);
  float* rnT     = alloc(Kn);
  float* rnW     = alloc(Vn);
  float* mu      = alloc(Kn);
  float* ivar    = alloc(Kn);
  float* errp    = alloc((size_t)NCH * Bn);
  float* Lb      = alloc(Bn);
  int* frozen = (int*)(ws + off); off += 64;
  if (off * sizeof(float) > ws_size) return;
  // R1 epoch views:
  u16*   nw_hi  = (u16*)R1;
  u16*   nw_lo  = nw_hi + (size_t)Vn * E3;
  float* w1part = R1;
  u16*   bm_bf  = (u16*)R1;
  u16*   vb_bf  = bm_bf + (size_t)Bn * Vpad;
  u16*   rbuf   = kern_bf;   // recon logits overwrite kern_bf/kernT post-loop

  hipMemsetAsync(frozen, 0, sizeof(int), stream);

  // ---- topic_word -> kern/kc/cost bf16 (+transposes) ----
  rowNorms<<<CDIV(Kn, 4), 256, 0, stream>>>(temb, rnT, Kn, En);
  rowNorms<<<CDIV(Vn, 4), 256, 0, stream>>>(wemb, rnW, Vn, En);
  convTemb<<<Kp, E3, 0, stream>>>(temb, rnT, nt_hi, nt_lo);
  convWemb<<<4096, 256, 0, stream>>>(wemb, rnW, nw_hi, nw_lo);
  gemmTW<<<Vpad / 64, 256, 0, stream>>>(nt_hi, nt_lo, nw_hi, nw_lo, kern_bf, kc_bf, cost_bf);
  transposeK<<<dim3(Vpad / 32, Kp / 32), 256, 0, stream>>>(kern_bf, kernT);
  transposeK<<<dim3(Vpad / 32, Kp / 32), 256, 0, stream>>>(cost_bf, costT);

  // ---- encoder (W1 partials clobber nw -- dead after gemmTW) ----
  gemmW1<<<8 * SW1, 256, 0, stream>>>(bows, W1, w1part);
  epiH<<<CDIV(Bn * Hn, 256), 256, 0, stream>>>(w1part, b1, hbuf, SW1);
  {
    dim3 g(CDIV(Kn, 64), CDIV(Bn, 64), 4);
    gemm_nt<<<g, 256, 0, stream>>>(hbuf, W2, w2buf, Bn, Kn, Hn);
  }
  bnStats<<<Kn, 256, 0, stream>>>(w2buf, b2, mu, ivar, 4);
  bnSoftmax<<<Bn, 256, 0, stream>>>(w2buf, b2, mu, ivar, gamma, beta, abuf, dt_bf, 4);
  rowSoftmax2<<<Bn, 512, 0, stream>>>(bows, bm_bf);   // clobbers dead W1 partials
  initU2<<<Bn, Kp, 0, stream>>>(ub_bf);

  // ---- sinkhorn loop (MFMA fused, natural grid order) ----
  dim3 gF(NCH, Bn / 64);
  for (int it = 0; it < NIT; ++it) {
    fusedAB<0><<<gF, 256, 0, stream>>>(kernT, kern_bf, ub_bf, bm_bf, nullptr, nullptr, tpart, nullptr, frozen);
    updateU2<<<Kn, 256, 0, stream>>>(tpart, abuf, ub_bf, frozen);
    if (it % 20 == 0) {
      fusedAB<1><<<gF, 256, 0, stream>>>(kernT, kern_bf, ub_bf, bm_bf, vb_bf, nullptr, tpart, nullptr, frozen);
      updateU2<<<Kn, 256, 0, stream>>>(tpart, abuf, ub_bf, frozen);
      fusedAB<2><<<gF, 256, 0, stream>>>(kernT, kern_bf, ub_bf, bm_bf, nullptr, vb_bf, tpart, errp, frozen);
      errFin<<<1, 256, 0, stream>>>(errp, NCH, frozen);
    }
  }

  // ---- reconstruction loss (MFMA; rbuf overwrites dead kern_bf/kernT) ----
  reconMF<<<dim3(NCH, Bn / 64), 256, 0, stream>>>(costT, dt_bf, rbuf);
  recPass2<<<Bn, 512, 0, stream>>>(rbuf, bows, Lb);

  // ---- sinkhorn loss ----
  fusedAB<3><<<gF, 256, 0, stream>>>(nullptr, kc_bf, ub_bf, nullptr, nullptr, vb_bf, tpart, nullptr, frozen);
  sumT<<<Kn, 256, 0, stream>>>(tpart, t2);
  finalOut<<<1, 256, 0, stream>>>(ub_bf, t2, Lb, out);
}

// Round 16
// 2270.389 us; speedup vs baseline: 1.5177x; 1.0093x over previous
//
#include <hip/hip_runtime.h>
#include <math.h>

#define CDIV(a,b) (((a)+(b)-1)/(b))

typedef unsigned short u16;
typedef unsigned long long u64;
typedef __attribute__((ext_vector_type(8))) short bf16x8;
typedef __attribute__((ext_vector_type(4))) float f32x4;

constexpr int Bn = 256;
constexpr int Vn = 30000;
constexpr int Hn = 512;
constexpr int Kn = 200;
constexpr int En = 300;
constexpr int E3 = 320;          // En padded for MFMA
constexpr int Kp = 224;          // K padded to 7*32
constexpr int Vc = 224;          // v-chunk per block
constexpr int NCH = 136;         // chunks, natural grid order
constexpr int Vpad = NCH * Vc;   // 30464
constexpr int SW1 = 64;          // W1 gemm k-slices
constexpr int KSL = 480;         // W1 k-slice length
constexpr float ALPHA  = 20.0f;
constexpr float RECW   = 0.7f;
constexpr float THRC   = 0.005f;
constexpr float EPS_BN = 1e-3f;
constexpr int   NIT    = 100;

__device__ __forceinline__ float bf2f(u16 h) {
  union { unsigned u; float f; } c; c.u = (unsigned)h << 16; return c.f;
}
__device__ __forceinline__ u16 f2bf(float f) {
  union { float f; unsigned u; } c; c.f = f;
  return (u16)((c.u + 0x7fffu + ((c.u >> 16) & 1u)) >> 16);
}
__device__ __forceinline__ bf16x8 load8bf(const float* p) {
  float4 a = *(const float4*)p, b = *(const float4*)(p + 4);
  bf16x8 r;
  r[0] = (short)f2bf(a.x); r[1] = (short)f2bf(a.y);
  r[2] = (short)f2bf(a.z); r[3] = (short)f2bf(a.w);
  r[4] = (short)f2bf(b.x); r[5] = (short)f2bf(b.y);
  r[6] = (short)f2bf(b.z); r[7] = (short)f2bf(b.w);
  return r;
}

// ================= fused sinkhorn iteration (MFMA bf16) =================
// MODE 0: w = bm/(kernT@u) in LDS, then tpart = kern@w partials (bf16)
// MODE 1: MODE 0 + also store w to global wout (v1 for check iterations)
// MODE 2: err partials only: errp[c][b] = sum_v |win*(kernT@u) - bm|
// MODE 3: final loss: tpart = kernA@win (win from global, phase A skipped)
// launch_bounds(256,4): grid-capped 2 blocks/CU was the occupancy limiter
// (R10 profile: 17%); LDS 28.7KB allows 5/CU, VGPR ~52 allows 4 waves/EU.
template<int MODE>
__global__ __launch_bounds__(256, 4)
void fusedAB(const u16* __restrict__ kernT, const u16* __restrict__ kernA,
             const u16* __restrict__ ub, const u16* __restrict__ bmb,
             u16* __restrict__ wout, const u16* __restrict__ win,
             u16* __restrict__ tpart, float* __restrict__ errp,
             const int* __restrict__ frozen)
{
  if (MODE != 3 && frozen[0]) return;
  const int c = blockIdx.x, g = blockIdx.y;
  const int v0 = c * Vc, b0 = g * 64;
  const int tid = threadIdx.x;
  const int wv = tid >> 6, l = tid & 63, l15 = l & 15, lg = l >> 4;
  const int rloc = wv * 16 + l15;     // local b row (0..63) = D col
  const int bcol = b0 + rloc;         // global b
  __shared__ u16 wlds[64 * Vc];
  char* wbase = (char*)wlds;
  const int sw = (rloc & 3) << 4;     // XOR bank swizzle (bits 4-5, in-range)

  if (MODE != 3) {
    // ---- phase A: denom[v][b] = sum_k kernT[v][k] * u[k][b] ----
    bf16x8 uf[7];
    {
      const u16* up = ub + (size_t)bcol * Kp + lg * 8;
#pragma unroll
      for (int ks = 0; ks < 7; ++ks) uf[ks] = *(const bf16x8*)(up + ks * 32);
    }
    float e = 0.f;
    for (int vt = 0; vt < Vc / 16; ++vt) {
      const u16* ktp = kernT + (size_t)(v0 + vt * 16 + l15) * Kp + lg * 8;
      f32x4 acc = {0.f, 0.f, 0.f, 0.f};
#pragma unroll
      for (int ks = 0; ks < 7; ++ks) {
        bf16x8 kf = *(const bf16x8*)(ktp + ks * 32);
        acc = __builtin_amdgcn_mfma_f32_16x16x32_bf16(kf, uf[ks], acc, 0, 0, 0);
      }
      const int vbase = v0 + vt * 16 + lg * 4;       // global v of acc[0]
      const size_t po = (size_t)bcol * Vpad + vbase;
      u64 bq = *(const u64*)(bmb + po);
      if (MODE == 2) {
        u64 wq = *(const u64*)(win + po);
#pragma unroll
        for (int r = 0; r < 4; ++r) {
          float bm = bf2f((u16)(bq >> (16 * r)));
          float wv_ = bf2f((u16)(wq >> (16 * r)));
          e += fabsf(wv_ * acc[r] - bm);
        }
      } else {
        u64 wq = 0;
#pragma unroll
        for (int r = 0; r < 4; ++r) {
          float bm = bf2f((u16)(bq >> (16 * r)));
          float w = (vbase + r < Vn) ? bm / acc[r] : 0.f;
          wq |= (u64)f2bf(w) << (16 * r);
        }
        *(u64*)(wbase + rloc * (Vc * 2) + ((vt * 32 + lg * 8) ^ sw)) = wq;
        if (MODE == 1) *(u64*)(wout + po) = wq;
      }
    }
    if (MODE == 2) {
      e += __shfl_xor(e, 16, 64);
      e += __shfl_xor(e, 32, 64);
      if (l < 16) errp[c * Bn + bcol] = e;
      return;
    }
    __syncthreads();
  }

  // ---- phase B: tpart[c][k][b] = sum_{v in chunk} kernA[k][v] * w[b][v] ----
  f32x4 accB[13];
#pragma unroll
  for (int mt = 0; mt < 13; ++mt) accB[mt] = (f32x4){0.f, 0.f, 0.f, 0.f};
  for (int vs = 0; vs < Vc / 32; ++vs) {
    bf16x8 wf;
    if (MODE == 3) wf = *(const bf16x8*)(win + (size_t)bcol * Vpad + v0 + vs * 32 + lg * 8);
    else wf = *(const bf16x8*)(wbase + rloc * (Vc * 2) + (((vs * 32 + lg * 8) * 2) ^ sw));
    const u16* kap = kernA + (size_t)l15 * Vpad + v0 + vs * 32 + lg * 8;
#pragma unroll
    for (int mt = 0; mt < 13; ++mt) {
      bf16x8 af = *(const bf16x8*)(kap + (size_t)mt * 16 * Vpad);
      accB[mt] = __builtin_amdgcn_mfma_f32_16x16x32_bf16(af, wf, accB[mt], 0, 0, 0);
    }
  }
#pragma unroll
  for (int mt = 0; mt < 13; ++mt) {
#pragma unroll
    for (int r = 0; r < 4; ++r) {
      int k = mt * 16 + lg * 4 + r;
      if (k < Kn) tpart[((size_t)c * Kn + k) * Bn + bcol] = f2bf(accB[mt][r]);
    }
  }
}

// ================= recon logits via MFMA: r[b][v] = 1 - sum_k costT[v][k]*dt[k][b] ====
__global__ __launch_bounds__(256, 4)
void reconMF(const u16* __restrict__ costT, const u16* __restrict__ dtb,
             u16* __restrict__ rbuf)
{
  const int c = blockIdx.x, g = blockIdx.y;
  const int v0 = c * Vc, b0 = g * 64;
  const int tid = threadIdx.x;
  const int wv = tid >> 6, l = tid & 63, l15 = l & 15, lg = l >> 4;
  const int bcol = b0 + wv * 16 + l15;
  bf16x8 uf[7];
  {
    const u16* up = dtb + (size_t)bcol * Kp + lg * 8;
#pragma unroll
    for (int ks = 0; ks < 7; ++ks) uf[ks] = *(const bf16x8*)(up + ks * 32);
  }
  for (int vt = 0; vt < Vc / 16; ++vt) {
    const u16* ktp = costT + (size_t)(v0 + vt * 16 + l15) * Kp + lg * 8;
    f32x4 acc = {0.f, 0.f, 0.f, 0.f};
#pragma unroll
    for (int ks = 0; ks < 7; ++ks) {
      bf16x8 kf = *(const bf16x8*)(ktp + ks * 32);
      acc = __builtin_amdgcn_mfma_f32_16x16x32_bf16(kf, uf[ks], acc, 0, 0, 0);
    }
    const int vbase = v0 + vt * 16 + lg * 4;
    u64 q = 0;
#pragma unroll
    for (int r = 0; r < 4; ++r) q |= (u64)f2bf(1.f - acc[r]) << (16 * r);
    *(u64*)(rbuf + (size_t)bcol * Vpad + vbase) = q;
  }
}

// ================= topic-word GEMM (MFMA, hi/lo bf16 split) =================
__global__ __launch_bounds__(256)
void gemmTW(const u16* __restrict__ nth, const u16* __restrict__ ntl,
            const u16* __restrict__ nwh, const u16* __restrict__ nwl,
            u16* __restrict__ kern_bf, u16* __restrict__ kc_bf,
            u16* __restrict__ cost_bf)
{
  const int n0 = blockIdx.x * 64;
  const int tid = threadIdx.x;
  const int wv = tid >> 6, l = tid & 63, l15 = l & 15, lg = l >> 4;
  const int n = n0 + wv * 16 + l15;     // v column
  const bool nok = n < Vn;
  f32x4 acc[14];
#pragma unroll
  for (int mt = 0; mt < 14; ++mt) acc[mt] = (f32x4){0.f, 0.f, 0.f, 0.f};
  for (int kc = 0; kc < E3; kc += 32) {
    bf16x8 bh = {0,0,0,0,0,0,0,0}, bl = {0,0,0,0,0,0,0,0};
    if (nok) {
      const size_t o = (size_t)n * E3 + kc + lg * 8;
      bh = *(const bf16x8*)(nwh + o);
      bl = *(const bf16x8*)(nwl + o);
    }
#pragma unroll
    for (int mt = 0; mt < 14; ++mt) {
      const size_t ao = (size_t)(mt * 16 + l15) * E3 + kc + lg * 8;
      bf16x8 ah = *(const bf16x8*)(nth + ao);
      bf16x8 al = *(const bf16x8*)(ntl + ao);
      acc[mt] = __builtin_amdgcn_mfma_f32_16x16x32_bf16(ah, bh, acc[mt], 0, 0, 0);
      acc[mt] = __builtin_amdgcn_mfma_f32_16x16x32_bf16(ah, bl, acc[mt], 0, 0, 0);
      acc[mt] = __builtin_amdgcn_mfma_f32_16x16x32_bf16(al, bh, acc[mt], 0, 0, 0);
    }
  }
#pragma unroll
  for (int mt = 0; mt < 14; ++mt) {
#pragma unroll
    for (int r = 0; r < 4; ++r) {
      int k = mt * 16 + lg * 4 + r;
      float cf = 1.f - acc[mt][r];
      float kf = expf(-ALPHA * cf);
      size_t o = (size_t)k * Vpad + n;
      kern_bf[o] = f2bf(kf);
      kc_bf[o]   = f2bf(kf * cf);
      cost_bf[o] = f2bf(cf);
    }
  }
}

// ================= W1 encoder GEMM (m-split: grid 1024, 4 blocks/CU) ==========
// part[s][b][h] = sum_{k in slice s} bows[b][k] * W1[h][k]
// Grid 512 capped occupancy at exactly 2 blocks/CU (r15 counters: 21%);
// halving the m-tile doubles the grid at identical total traffic.
__global__ __launch_bounds__(256)
void gemmW1(const float* __restrict__ A, const float* __restrict__ B,
            float* __restrict__ part)
{
  const int bid = blockIdx.x;             // 1024
  const int xcd = bid & 7, t = bid >> 3;  // 0..127
  const int s = xcd * 8 + (t >> 4);       // same-s blocks share an XCD's L2
  const int sub = t & 15;
  const int m0 = (sub >> 3) * 128;        // m-half
  const int nx = sub & 7;
  const int n0 = nx * 64, k0 = s * KSL;
  const int tid = threadIdx.x;
  const int wv = tid >> 6, l = tid & 63, l15 = l & 15, lg = l >> 4;
  f32x4 acc[2][4];
#pragma unroll
  for (int i = 0; i < 2; ++i)
#pragma unroll
    for (int j = 0; j < 4; ++j) acc[i][j] = (f32x4){0.f, 0.f, 0.f, 0.f};

  bf16x8 aA[2], bA[4], aB[2], bB[4];

#define LDW1(KC, AF, BF)                                                        \
  { const int kk_ = (KC) + lg * 8;                                              \
    const bool ok_ = kk_ < Vn;                                                  \
    _Pragma("unroll")                                                           \
    for (int mt = 0; mt < 2; ++mt) {                                            \
      const int m_ = m0 + wv * 32 + mt * 16 + l15;                              \
      AF[mt] = ok_ ? load8bf(A + (size_t)m_ * Vn + kk_) : (bf16x8){0,0,0,0,0,0,0,0}; \
    }                                                                           \
    _Pragma("unroll")                                                           \
    for (int nt = 0; nt < 4; ++nt) {                                            \
      const int n_ = n0 + nt * 16 + l15;                                        \
      BF[nt] = ok_ ? load8bf(B + (size_t)n_ * Vn + kk_) : (bf16x8){0,0,0,0,0,0,0,0}; \
    } }

#define FMAW1(AF, BF)                                                           \
  _Pragma("unroll")                                                             \
  for (int mt = 0; mt < 2; ++mt)                                                \
    _Pragma("unroll")                                                           \
    for (int nt = 0; nt < 4; ++nt)                                              \
      acc[mt][nt] = __builtin_amdgcn_mfma_f32_16x16x32_bf16(AF[mt], BF[nt], acc[mt][nt], 0, 0, 0);

  LDW1(k0, aA, bA);
#pragma unroll
  for (int step = 0; step < KSL / 32; ++step) {
    if ((step & 1) == 0) {
      if (step + 1 < KSL / 32) LDW1(k0 + (step + 1) * 32, aB, bB);
      FMAW1(aA, bA);
    } else {
      if (step + 1 < KSL / 32) LDW1(k0 + (step + 1) * 32, aA, bA);
      FMAW1(aB, bB);
    }
  }
#undef LDW1
#undef FMAW1

#pragma unroll
  for (int mt = 0; mt < 2; ++mt)
#pragma unroll
    for (int nt = 0; nt < 4; ++nt)
#pragma unroll
      for (int r = 0; r < 4; ++r) {
        const int m = m0 + wv * 32 + mt * 16 + lg * 4 + r;
        const int n = n0 + nt * 16 + l15;
        part[(size_t)s * (Bn * Hn) + (size_t)m * Hn + n] = acc[mt][nt][r];
      }
}

// ================= prep: transpose bf16 [Kp][Vpad] -> [Vpad][Kp] =================
__global__ void transposeK(const u16* __restrict__ src, u16* __restrict__ dst)
{
  __shared__ u16 t[32][33];
  int tx = threadIdx.x & 31, ty = threadIdx.x >> 5;  // 32 x 8
  int v0 = blockIdx.x * 32, k0 = blockIdx.y * 32;
#pragma unroll
  for (int r = 0; r < 4; ++r) t[ty + 8 * r][tx] = src[(size_t)(k0 + ty + 8 * r) * Vpad + v0 + tx];
  __syncthreads();
#pragma unroll
  for (int r = 0; r < 4; ++r) dst[(size_t)(v0 + ty + 8 * r) * Kp + k0 + tx] = t[tx][ty + 8 * r];
}

// ================= embedding converts (normalized, hi/lo split) =================
__global__ void convTemb(const float* __restrict__ temb, const float* __restrict__ rnT,
                         u16* __restrict__ nth, u16* __restrict__ ntl)
{
  int k = blockIdx.x, e = threadIdx.x;   // Kp x 320
  float v = (k < Kn && e < En) ? temb[(size_t)k * En + e] * rnT[k] : 0.f;
  u16 hi = f2bf(v);
  nth[(size_t)k * E3 + e] = hi;
  ntl[(size_t)k * E3 + e] = f2bf(v - bf2f(hi));
}

__global__ void convWemb(const float* __restrict__ wemb, const float* __restrict__ rnW,
                         u16* __restrict__ nwh, u16* __restrict__ nwl)
{
  for (size_t idx = (size_t)blockIdx.x * 256 + threadIdx.x; idx < (size_t)Vn * E3;
       idx += (size_t)gridDim.x * 256) {
    int v = (int)(idx / E3), e = (int)(idx - (size_t)v * E3);
    float x = (e < En) ? wemb[(size_t)v * En + e] * rnW[v] : 0.f;
    u16 hi = f2bf(x);
    nwh[idx] = hi;
    nwl[idx] = f2bf(x - bf2f(hi));
  }
}

// ================= generic f32 NT GEMM (W2 only) =================
__global__ __launch_bounds__(256)
void gemm_nt(const float* __restrict__ A, const float* __restrict__ Bm,
             float* __restrict__ P, int M, int N, int Kd)
{
  const int S = gridDim.z, s = blockIdx.z;
  const int k0 = (int)((long long)Kd * s / S);
  const int k1 = (int)((long long)Kd * (s + 1) / S);
  const int m0 = blockIdx.y * 64, n0 = blockIdx.x * 64;
  __shared__ float As[16][68];
  __shared__ float Bs[16][68];
  const int tid = threadIdx.x;
  const int tx = tid & 15, ty = tid >> 4;
  const int lrow = tid >> 2, lkg = (tid & 3) * 4;
  const int mi = m0 + lrow, ni = n0 + lrow;
  float acc[4][4] = {};
  for (int kc = k0; kc < k1; kc += 16) {
    float4 a4 = {0.f, 0.f, 0.f, 0.f}, b4 = {0.f, 0.f, 0.f, 0.f};
    if (mi < M) a4 = *(const float4*)&A[(size_t)mi * Kd + kc + lkg];
    if (ni < N) b4 = *(const float4*)&Bm[(size_t)ni * Kd + kc + lkg];
    As[lkg + 0][lrow] = a4.x; As[lkg + 1][lrow] = a4.y;
    As[lkg + 2][lrow] = a4.z; As[lkg + 3][lrow] = a4.w;
    Bs[lkg + 0][lrow] = b4.x; Bs[lkg + 1][lrow] = b4.y;
    Bs[lkg + 2][lrow] = b4.z; Bs[lkg + 3][lrow] = b4.w;
    __syncthreads();
#pragma unroll
    for (int kk = 0; kk < 16; ++kk) {
      float4 av = *(const float4*)&As[kk][ty * 4];
      float4 bv = *(const float4*)&Bs[kk][tx * 4];
      float a_[4] = {av.x, av.y, av.z, av.w};
      float b_[4] = {bv.x, bv.y, bv.z, bv.w};
#pragma unroll
      for (int i = 0; i < 4; ++i)
#pragma unroll
        for (int j = 0; j < 4; ++j)
          acc[i][j] += a_[i] * b_[j];
    }
    __syncthreads();
  }
  const size_t base = (size_t)s * M * N;
#pragma unroll
  for (int i = 0; i < 4; ++i) {
    int m = m0 + ty * 4 + i;
    if (m >= M) continue;
#pragma unroll
    for (int j = 0; j < 4; ++j) {
      int n = n0 + tx * 4 + j;
      if (n < N) P[base + (size_t)m * N + n] = acc[i][j];
    }
  }
}

// ================= small kernels =================
__global__ void rowNorms(const float* __restrict__ X, float* __restrict__ rn, int R, int C)
{
  int wv = threadIdx.x >> 6, lane = threadIdx.x & 63;
  int r = blockIdx.x * 4 + wv;
  if (r >= R) return;
  float s = 0.f;
  for (int c = lane; c < C; c += 64) { float x = X[(size_t)r * C + c]; s += x * x; }
#pragma unroll
  for (int m = 32; m; m >>= 1) s += __shfl_xor(s, m, 64);
  if (lane == 0) rn[r] = 1.f / fmaxf(sqrtf(s), 1e-12f);
}

__global__ void epiH(const float* __restrict__ P, const float* __restrict__ b1,
                     float* __restrict__ h, int S)
{
  int i = blockIdx.x * blockDim.x + threadIdx.x;
  if (i >= Bn * Hn) return;
  float v = b1[i & (Hn - 1)];
#pragma unroll 8
  for (int s = 0; s < S; ++s) v += P[(size_t)s * Bn * Hn + i];
  h[i] = fmaxf(v, 0.f);
}

__global__ void bnStats(const float* __restrict__ P, const float* __restrict__ b2,
                        float* __restrict__ mu, float* __restrict__ ivar, int S)
{
  int k = blockIdx.x, b = threadIdx.x;
  float z = b2[k];
  for (int s = 0; s < S; ++s) z += P[((size_t)s * Bn + b) * Kn + k];
  __shared__ float r1[256], r2[256];
  r1[b] = z; r2[b] = z * z; __syncthreads();
  for (int st = 128; st; st >>= 1) {
    if (b < st) { r1[b] += r1[b + st]; r2[b] += r2[b + st]; }
    __syncthreads();
  }
  if (b == 0) {
    float m = r1[0] / Bn, v = r2[0] / Bn - (r1[0] / Bn) * (r1[0] / Bn);
    mu[k] = m; ivar[k] = rsqrtf(v + EPS_BN);
  }
}

__global__ void bnSoftmax(const float* __restrict__ P, const float* __restrict__ b2,
                          const float* __restrict__ mu, const float* __restrict__ ivar,
                          const float* __restrict__ gamma, const float* __restrict__ beta,
                          float* __restrict__ a, u16* __restrict__ dtb, int S)
{
  int b = blockIdx.x, k = threadIdx.x;
  float zn = -1e30f;
  if (k < Kn) {
    float z = b2[k];
    for (int s = 0; s < S; ++s) z += P[((size_t)s * Bn + b) * Kn + k];
    zn = gamma[k] * (z - mu[k]) * ivar[k] + beta[k];
  }
  __shared__ float red[256];
  red[k] = zn; __syncthreads();
  for (int st = 128; st; st >>= 1) { if (k < st) red[k] = fmaxf(red[k], red[k + st]); __syncthreads(); }
  float mx = red[0]; __syncthreads();
  float e = (k < Kn) ? expf(zn - mx) : 0.f;
  red[k] = e; __syncthreads();
  for (int st = 128; st; st >>= 1) { if (k < st) red[k] += red[k + st]; __syncthreads(); }
  float dt = e / red[0];
  if (k < Kn) a[(size_t)k * Bn + b] = dt;
  if (k < Kp) dtb[(size_t)b * Kp + k] = (k < Kn) ? f2bf(dt) : (u16)0;
}

__global__ __launch_bounds__(512)
void rowSoftmax2(const float* __restrict__ bows, u16* __restrict__ bmb)
{
  int b = blockIdx.x, t = threadIdx.x;
  const float4* row = (const float4*)(bows + (size_t)b * Vn);
  __shared__ float red[512];
  float mx = -1e30f;
  for (int v4 = t; v4 < Vn / 4; v4 += 512) {
    float4 x = row[v4];
    mx = fmaxf(mx, fmaxf(fmaxf(x.x, x.y), fmaxf(x.z, x.w)));
  }
  red[t] = mx; __syncthreads();
  for (int st = 256; st; st >>= 1) { if (t < st) red[t] = fmaxf(red[t], red[t + st]); __syncthreads(); }
  mx = red[0]; __syncthreads();
  float sum = 0.f;
  for (int v4 = t; v4 < Vn / 4; v4 += 512) {
    float4 x = row[v4];
    sum += expf(x.x - mx) + expf(x.y - mx) + expf(x.z - mx) + expf(x.w - mx);
  }
  red[t] = sum; __syncthreads();
  for (int st = 256; st; st >>= 1) { if (t < st) red[t] += red[t + st]; __syncthreads(); }
  float inv = 1.f / red[0];
  for (int v4 = t; v4 < Vn / 4; v4 += 512) {
    float4 x = row[v4];
    u64 q = (u64)f2bf(expf(x.x - mx) * inv)
          | ((u64)f2bf(expf(x.y - mx) * inv) << 16)
          | ((u64)f2bf(expf(x.z - mx) * inv) << 32)
          | ((u64)f2bf(expf(x.w - mx) * inv) << 48);
    *(u64*)(bmb + (size_t)b * Vpad + v4 * 4) = q;
  }
  for (int p = t; p < (Vpad - Vn) / 4; p += 512)
    *(u64*)(bmb + (size_t)b * Vpad + Vn + p * 4) = 0;
}

__global__ void initU2(u16* __restrict__ ub)
{
  int b = blockIdx.x, k = threadIdx.x;   // Bn blocks x Kp threads
  ub[(size_t)b * Kp + k] = (k < Kn) ? f2bf(1.f / Kn) : (u16)0;
}

// 200 blocks (one k each); 64 b-quads x 4 c-groups; LDS reduce over c-groups.
__global__ __launch_bounds__(256)
void updateU2(const u16* __restrict__ tpart, const float* __restrict__ a,
              u16* __restrict__ ub, const int* __restrict__ frozen)
{
  if (frozen[0]) return;
  const int k = blockIdx.x;
  const int cg = threadIdx.x >> 6, q = threadIdx.x & 63;
  const int b0 = q * 4;
  f32x4 t = {0.f, 0.f, 0.f, 0.f};
  for (int c = cg * (NCH / 4); c < (cg + 1) * (NCH / 4); ++c) {
    u64 qd = *(const u64*)(tpart + ((size_t)c * Kn + k) * Bn + b0);
    t[0] += bf2f((u16)qd);         t[1] += bf2f((u16)(qd >> 16));
    t[2] += bf2f((u16)(qd >> 32)); t[3] += bf2f((u16)(qd >> 48));
  }
  __shared__ f32x4 red[4][64];
  red[cg][q] = t;
  __syncthreads();
  if (cg == 0) {
    f32x4 s = red[0][q];
#pragma unroll
    for (int gg = 1; gg < 4; ++gg) {
      f32x4 o = red[gg][q];
      s[0] += o[0]; s[1] += o[1]; s[2] += o[2]; s[3] += o[3];
    }
    float4 av = *(const float4*)&a[(size_t)k * Bn + b0];
    ub[(size_t)(b0 + 0) * Kp + k] = f2bf(av.x / s[0]);
    ub[(size_t)(b0 + 1) * Kp + k] = f2bf(av.y / s[1]);
    ub[(size_t)(b0 + 2) * Kp + k] = f2bf(av.z / s[2]);
    ub[(size_t)(b0 + 3) * Kp + k] = f2bf(av.w / s[3]);
  }
}

__global__ __launch_bounds__(256)
void sumT(const u16* __restrict__ tpart, float* __restrict__ t2)
{
  const int k = blockIdx.x;
  const int cg = threadIdx.x >> 6, q = threadIdx.x & 63;
  const int b0 = q * 4;
  f32x4 t = {0.f, 0.f, 0.f, 0.f};
  for (int c = cg * (NCH / 4); c < (cg + 1) * (NCH / 4); ++c) {
    u64 qd = *(const u64*)(tpart + ((size_t)c * Kn + k) * Bn + b0);
    t[0] += bf2f((u16)qd);         t[1] += bf2f((u16)(qd >> 16));
    t[2] += bf2f((u16)(qd >> 32)); t[3] += bf2f((u16)(qd >> 48));
  }
  __shared__ f32x4 red[4][64];
  red[cg][q] = t;
  __syncthreads();
  if (cg == 0) {
    f32x4 s = red[0][q];
#pragma unroll
    for (int gg = 1; gg < 4; ++gg) {
      f32x4 o = red[gg][q];
      s[0] += o[0]; s[1] += o[1]; s[2] += o[2]; s[3] += o[3];
    }
    float4 ov; ov.x = s[0]; ov.y = s[1]; ov.z = s[2]; ov.w = s[3];
    *(float4*)&t2[(size_t)k * Bn + b0] = ov;
  }
}

__global__ void errFin(const float* __restrict__ errp, int nc, int* __restrict__ frozen)
{
  if (frozen[0]) return;
  int b = threadIdx.x;
  float s = 0.f;
  for (int c = 0; c < nc; ++c) s += errp[(size_t)c * Bn + b];
  __shared__ float red[256];
  red[b] = s; __syncthreads();
  for (int st = 128; st; st >>= 1) { if (b < st) red[b] = fmaxf(red[b], red[b + st]); __syncthreads(); }
  if (b == 0 && red[0] <= THRC) frozen[0] = 1;
}

__global__ __launch_bounds__(512)
void recPass2(const u16* __restrict__ r, const float* __restrict__ bows,
              float* __restrict__ Lb)
{
  int b = blockIdx.x, t = threadIdx.x;
  const float m = 1.0f;   // logits r = 1 - dot(dt,cost) <= 1 always
  const float4* br = (const float4*)(bows + (size_t)b * Vn);
  float se = 0.f, dot = 0.f, bs = 0.f;
  for (int v4 = t; v4 < Vn / 4; v4 += 512) {
    u64 q = *(const u64*)(r + (size_t)b * Vpad + v4 * 4);
    float4 w = br[v4];
    float x0 = bf2f((u16)q), x1 = bf2f((u16)(q >> 16));
    float x2 = bf2f((u16)(q >> 32)), x3 = bf2f((u16)(q >> 48));
    se  += expf(x0 - m) + expf(x1 - m) + expf(x2 - m) + expf(x3 - m);
    dot += w.x * x0 + w.y * x1 + w.z * x2 + w.w * x3;
    bs  += w.x + w.y + w.z + w.w;
  }
  __shared__ float red[512];
  red[t] = se; __syncthreads();
  for (int st = 256; st; st >>= 1) { if (t < st) red[t] += red[t + st]; __syncthreads(); }
  float seT = red[0]; __syncthreads();
  red[t] = dot; __syncthreads();
  for (int st = 256; st; st >>= 1) { if (t < st) red[t] += red[t + st]; __syncthreads(); }
  float dotT = red[0]; __syncthreads();
  red[t] = bs; __syncthreads();
  for (int st = 256; st; st >>= 1) { if (t < st) red[t] += red[t + st]; __syncthreads(); }
  if (t == 0) Lb[b] = dotT - (m + logf(seT)) * red[0];
}

__global__ void finalOut(const u16* __restrict__ ub, const float* __restrict__ t2,
                         const float* __restrict__ Lb, float* __restrict__ outp)
{
  int b = threadIdx.x;
  float sl = 0.f;
  for (int k = 0; k < Kn; ++k) sl += bf2f(ub[(size_t)b * Kp + k]) * t2[(size_t)k * Bn + b];
  __shared__ float r1[256], r2[256];
  r1[b] = sl; r2[b] = Lb[b]; __syncthreads();
  for (int st = 128; st; st >>= 1) {
    if (b < st) { r1[b] += r1[b + st]; r2[b] += r2[b + st]; }
    __syncthreads();
  }
  if (b == 0) {
    outp[0] = RECW * (-(r2[0] / (float)Bn));
    outp[1] = r1[0] / (float)Bn;
  }
}

extern "C" void kernel_launch(void* const* d_in, const int* in_sizes, int n_in,
                              void* d_out, int out_size, void* d_ws, size_t ws_size,
                              hipStream_t stream)
{
  const float* bows  = (const float*)d_in[0];
  const float* W1    = (const float*)d_in[1];
  const float* b1    = (const float*)d_in[2];
  const float* W2    = (const float*)d_in[3];
  const float* b2    = (const float*)d_in[4];
  const float* gamma = (const float*)d_in[5];
  const float* beta  = (const float*)d_in[6];
  const float* wemb  = (const float*)d_in[7];
  const float* temb  = (const float*)d_in[8];
  float* out = (float*)d_out;

  float* ws = (float*)d_ws;
  size_t off = 0;
  auto alloc = [&](size_t n) { float* p = ws + off; off += (n + 63) & ~(size_t)63; return p; };
  // R1: multi-epoch region. Epoch1: nw_hi/nw_lo (38.4MB). Epoch2: W1 partials
  // (33.5MB). Epoch3: bm_bf + vb_bf (31.2MB). Lifetimes strictly sequential.
  size_t r1_floats = (size_t)Vn * E3;
  if ((size_t)SW1 * Bn * Hn > r1_floats) r1_floats = (size_t)SW1 * Bn * Hn;
  float* R1      = alloc(r1_floats);
  u16*   kern_bf = (u16*)alloc(((size_t)Kp * Vpad + 1) / 2);
  u16*   kernT   = (u16*)alloc(((size_t)Vpad * Kp + 1) / 2);
  u16*   kc_bf   = (u16*)alloc(((size_t)Kp * Vpad + 1) / 2);
  u16*   cost_bf = (u16*)alloc(((size_t)Kp * Vpad + 1) / 2);
  u16*   costT   = (u16*)alloc(((size_t)Vpad * Kp + 1) / 2);
  u16*   nt_hi   = (u16*)alloc(((size_t)Kp * E3 + 1) / 2);
  u16*   nt_lo   = (u16*)alloc(((size_t)Kp * E3 + 1) / 2);
  u16*   ub_bf   = (u16*)alloc(((size_t)Bn * Kp + 1) / 2);
  u16*   dt_bf   = (u16*)alloc(((size_t)Bn * Kp + 1) / 2);
  u16*   tpart   = (u16*)alloc(((size_t)NCH * Kn * Bn + 1) / 2);
  float* w2buf   = alloc((size_t)4 * Bn * Kn);
  float* hbuf    = alloc((size_t)Bn * Hn);
  float* abuf    = alloc((size_t)Kn * Bn);
  float* t2      = alloc((size_t)Kn * Bn);
  float* rnT     = alloc(Kn);
  float* rnW     = alloc(Vn);
  float* mu      = alloc(Kn);
  float* ivar    = alloc(Kn);
  float* errp    = alloc((size_t)NCH * Bn);
  float* Lb      = alloc(Bn);
  int* frozen = (int*)(ws + off); off += 64;
  if (off * sizeof(float) > ws_size) return;
  // R1 epoch views:
  u16*   nw_hi  = (u16*)R1;
  u16*   nw_lo  = nw_hi + (size_t)Vn * E3;
  float* w1part = R1;
  u16*   bm_bf  = (u16*)R1;
  u16*   vb_bf  = bm_bf + (size_t)Bn * Vpad;
  u16*   rbuf   = kern_bf;   // recon logits overwrite kern_bf/kernT post-loop

  hipMemsetAsync(frozen, 0, sizeof(int), stream);

  // ---- topic_word -> kern/kc/cost bf16 (+transposes) ----
  rowNorms<<<CDIV(Kn, 4), 256, 0, stream>>>(temb, rnT, Kn, En);
  rowNorms<<<CDIV(Vn, 4), 256, 0, stream>>>(wemb, rnW, Vn, En);
  convTemb<<<Kp, E3, 0, stream>>>(temb, rnT, nt_hi, nt_lo);
  convWemb<<<4096, 256, 0, stream>>>(wemb, rnW, nw_hi, nw_lo);
  gemmTW<<<Vpad / 64, 256, 0, stream>>>(nt_hi, nt_lo, nw_hi, nw_lo, kern_bf, kc_bf, cost_bf);
  transposeK<<<dim3(Vpad / 32, Kp / 32), 256, 0, stream>>>(kern_bf, kernT);
  transposeK<<<dim3(Vpad / 32, Kp / 32), 256, 0, stream>>>(cost_bf, costT);

  // ---- encoder (W1 partials clobber nw -- dead after gemmTW) ----
  gemmW1<<<16 * SW1, 256, 0, stream>>>(bows, W1, w1part);
  epiH<<<CDIV(Bn * Hn, 256), 256, 0, stream>>>(w1part, b1, hbuf, SW1);
  {
    dim3 g(CDIV(Kn, 64), CDIV(Bn, 64), 4);
    gemm_nt<<<g, 256, 0, stream>>>(hbuf, W2, w2buf, Bn, Kn, Hn);
  }
  bnStats<<<Kn, 256, 0, stream>>>(w2buf, b2, mu, ivar, 4);
  bnSoftmax<<<Bn, 256, 0, stream>>>(w2buf, b2, mu, ivar, gamma, beta, abuf, dt_bf, 4);
  rowSoftmax2<<<Bn, 512, 0, stream>>>(bows, bm_bf);   // clobbers dead W1 partials
  initU2<<<Bn, Kp, 0, stream>>>(ub_bf);

  // ---- sinkhorn loop (MFMA fused, natural grid order) ----
  dim3 gF(NCH, Bn / 64);
  for (int it = 0; it < NIT; ++it) {
    fusedAB<0><<<gF, 256, 0, stream>>>(kernT, kern_bf, ub_bf, bm_bf, nullptr, nullptr, tpart, nullptr, frozen);
    updateU2<<<Kn, 256, 0, stream>>>(tpart, abuf, ub_bf, frozen);
    if (it % 20 == 0) {
      fusedAB<1><<<gF, 256, 0, stream>>>(kernT, kern_bf, ub_bf, bm_bf, vb_bf, nullptr, tpart, nullptr, frozen);
      updateU2<<<Kn, 256, 0, stream>>>(tpart, abuf, ub_bf, frozen);
      fusedAB<2><<<gF, 256, 0, stream>>>(kernT, kern_bf, ub_bf, bm_bf, nullptr, vb_bf, tpart, errp, frozen);
      errFin<<<1, 256, 0, stream>>>(errp, NCH, frozen);
    }
  }

  // ---- reconstruction loss (MFMA; rbuf overwrites dead kern_bf/kernT) ----
  reconMF<<<dim3(NCH, Bn / 64), 256, 0, stream>>>(costT, dt_bf, rbuf);
  recPass2<<<Bn, 512, 0, stream>>>(rbuf, bows, Lb);

  // ---- sinkhorn loss ----
  fusedAB<3><<<gF, 256, 0, stream>>>(nullptr, kc_bf, ub_bf, nullptr, nullptr, vb_bf, tpart, nullptr, frozen);
  sumT<<<Kn, 256, 0, stream>>>(tpart, t2);
  finalOut<<<1, 256, 0, stream>>>(ub_bf, t2, Lb, out);
}